// Round 7
// baseline (324.507 us; speedup 1.0000x reference)
//
#include <hip/hip_runtime.h>

#define B_    4
#define T_    2048
#define H_    1024
#define S_    512
#define HALF_ 256
#define LOC_  1024
#define BT_   8192          // B*T rows
#define N1_   6400          // proj cols: 8*512 + 256 + 1024 + 1024
#define K1_   1024
#define N2_   1024
#define K2_   2048
#define NCH_  32            // scan chunks
#define LC_   64            // chunk length (T_/NCH_)

typedef __attribute__((ext_vector_type(8))) short  bf16x8;
typedef __attribute__((ext_vector_type(4))) float  f32x4;
typedef __attribute__((ext_vector_type(4))) unsigned short u16x4;

__device__ __forceinline__ float b2f(unsigned short u) {
    union { unsigned i; float f; } v; v.i = ((unsigned)u) << 16; return v.f;
}
__device__ __forceinline__ unsigned short f2b(float f) {
    union { float f; unsigned i; } v; v.f = f;
    unsigned r = v.i + 0x7fffu + ((v.i >> 16) & 1u);
    return (unsigned short)(r >> 16);
}
__device__ __forceinline__ float rcp_(float x) { return __builtin_amdgcn_rcpf(x); }
__device__ __forceinline__ float sigm_(float v) { return rcp_(1.f + __expf(-v)); }
__device__ __forceinline__ float silu_(float v) { return v * rcp_(1.f + __expf(-v)); }
__device__ __forceinline__ float tanh_(float v) { return 1.f - 2.f * rcp_(1.f + __expf(2.f * v)); }

__device__ __forceinline__ void gload16(const void* g, void* l) {
    __builtin_amdgcn_global_load_lds(
        (const __attribute__((address_space(1))) void*)g,
        (__attribute__((address_space(3))) void*)l,
        16, 0, 0);
}

#define SB0 __builtin_amdgcn_sched_barrier(0)
#define BARR __builtin_amdgcn_s_barrier()
#define WAITVN(n) asm volatile("s_waitcnt vmcnt(" #n ")" ::: "memory")

// ---------------------------------------------------------------- pack x -> bf16
__global__ void pack_x_kernel(const float* __restrict__ x, unsigned short* __restrict__ xb) {
    int i = blockIdx.x * 256 + threadIdx.x;
    float4 a = ((const float4*)x)[i];
    u16x4 u;
    u.x = f2b(a.x); u.y = f2b(a.y); u.z = f2b(a.z); u.w = f2b(a.w);
    ((u16x4*)xb)[i] = u;
}

// ------------------------------------------------- transpose-pack weights to [n][k] bf16
struct TOp { const float* src; int Kw; int Nw; int n_ofs; int k_ofs; int which; };
struct TOps { TOp v[14]; };

__global__ void pack_w_kernel(TOps ops, unsigned short* __restrict__ w1, unsigned short* __restrict__ w2) {
    TOp op = ops.v[blockIdx.z];
    int kt = blockIdx.x * 32, nt = blockIdx.y * 32;
    if (kt >= op.Kw || nt >= op.Nw) return;
    __shared__ float tile[32][33];
    int tx = threadIdx.x & 31, ty = threadIdx.x >> 5;   // 32 x 8
#pragma unroll
    for (int r = 0; r < 4; r++) {
        int k = kt + ty + r * 8;
        tile[ty + r * 8][tx] = op.src[(size_t)k * op.Nw + nt + tx];
    }
    __syncthreads();
    unsigned short* dst = op.which ? w2 : w1;
    int stride = op.which ? K2_ : K1_;
#pragma unroll
    for (int r = 0; r < 4; r++) {
        int n = nt + ty + r * 8;
        dst[(size_t)(op.n_ofs + n) * stride + op.k_ofs + kt + tx] = f2b(tile[tx][ty + r * 8]);
    }
}

// ---------------------------------------------------------------- mix softmax (x @ W_mix)
__global__ void mix_kernel(const float* __restrict__ x, const float* __restrict__ Wm,
                           float4* __restrict__ mw) {
    int row  = blockIdx.x * 4 + (threadIdx.x >> 6);
    int lane = threadIdx.x & 63;
    const float* xr = x + (size_t)row * H_;
    float s0 = 0.f, s1 = 0.f, s2 = 0.f;
    for (int k = lane; k < H_; k += 64) {
        float xv = xr[k];
        s0 += xv * Wm[k * 3 + 0];
        s1 += xv * Wm[k * 3 + 1];
        s2 += xv * Wm[k * 3 + 2];
    }
#pragma unroll
    for (int off = 32; off; off >>= 1) {
        s0 += __shfl_down(s0, off);
        s1 += __shfl_down(s1, off);
        s2 += __shfl_down(s2, off);
    }
    if (lane == 0) {
        float m = fmaxf(s0, fmaxf(s1, s2));
        float e0 = __expf(s0 - m), e1 = __expf(s1 - m), e2 = __expf(s2 - m);
        float inv = 1.f / (e0 + e1 + e2);
        mw[row] = (float4){ e0 * inv, e1 * inv, e2 * inv, 0.f };
    }
}

// ================================================================ GEMM1: 256x256 tile,
// BK=32, 8 waves (2Mx4N, each 128x64 out), 4-buffer LDS ring (128KB), counted-vmcnt
// deep pipeline (issue t+3 during compute of t; wait vmcnt(8), never 0 mid-loop),
// slot-XOR LDS swizzle via pre-swizzled global source, setprio around MFMA cluster.
// Requires K % 128 == 0 (so last buffer index == 3, epilogue LDS reuse in buf0 is safe).
__global__ __launch_bounds__(512, 2) void gemm256_proj(
    const unsigned short* __restrict__ A,
    const unsigned short* __restrict__ Bt,
    unsigned short* __restrict__ proj,
    unsigned short* __restrict__ swb,
    const int M, const int N, const int K)
{
    __shared__ __align__(16) unsigned short smem[65536];   // 128 KB: 4 x (A 8192 + B 8192)
    const int tid  = threadIdx.x;
    const int wid  = tid >> 6;
    const int lane = tid & 63;
    const int wr = wid >> 2;          // 0..1 : wave row (128 rows)
    const int wc = wid & 3;           // 0..3 : wave col (64 cols)
    const int fr = lane & 15;
    const int h  = lane >> 4;

    // XCD swizzle (bijective: grid total % 8 == 0)
    const int flat = blockIdx.y * gridDim.x + blockIdx.x;
    const int xcd  = flat & 7;
    const int ii   = flat >> 3;
    const int mpx  = gridDim.y >> 3;                  // m-blocks per XCD
    const int bm   = (xcd * mpx + (ii % mpx)) * 256;
    const int bn   = (ii / mpx) * 256;

    f32x4 acc[8][4];
#pragma unroll
    for (int m = 0; m < 8; m++)
#pragma unroll
        for (int n = 0; n < 4; n++) acc[m][n] = (f32x4){0.f, 0.f, 0.f, 0.f};

    // staging: wave w stages rows [w*32, w*32+32) of A-tile and B-tile.
    // lane l -> row += l>>2, physical slot l&3; global logical slot = (l&3)^((l>>2)&3)
    const int rl  = lane >> 2;
    const int ssw = ((lane & 3) ^ (rl & 3)) * 8;
    const unsigned short* aS0 = A  + (size_t)(bm + wid * 32 + rl) * K + ssw;
    const unsigned short* aS1 = aS0 + (size_t)16 * K;
    const unsigned short* bS0 = Bt + (size_t)(bn + wid * 32 + rl) * K + ssw;
    const unsigned short* bS1 = bS0 + (size_t)16 * K;
    const int stgO = wid * 1024;                      // elem offset of wave's 32 rows

    // read swizzle: logical slot h of row r lives at physical slot h^(r&3); r&3 == fr&3
    const int rsw = (h ^ (fr & 3)) * 8;
    const int NT  = K >> 5;

#define ISSUE4(tt, cc) {                                        \
        const size_t ko = (size_t)(tt) * 32;                    \
        unsigned short* dA = smem + (cc) * 16384 + stgO;        \
        unsigned short* dB = smem + (cc) * 16384 + 8192 + stgO; \
        gload16(aS0 + ko, dA); gload16(aS1 + ko, dA + 512);     \
        gload16(bS0 + ko, dB); gload16(bS1 + ko, dB + 512); }

    ISSUE4(0, 0); ISSUE4(1, 1); ISSUE4(2, 2);        // 12 loads in flight
    SB0; WAITVN(8); SB0; BARR; SB0;                  // tile0 landed everywhere

    for (int t = 0; t < NT; ++t) {
        const int c = t & 3;
        const unsigned short* bufA = smem + c * 16384;
        const unsigned short* bufB = bufA + 8192;
        bf16x8 af[8], bfv[4];
#pragma unroll
        for (int m = 0; m < 8; m++)
            af[m] = *(const bf16x8*)(bufA + (wr * 128 + m * 16 + fr) * 32 + rsw);
#pragma unroll
        for (int n = 0; n < 4; n++)
            bfv[n] = *(const bf16x8*)(bufB + (wc * 64 + n * 16 + fr) * 32 + rsw);
        __builtin_amdgcn_s_setprio(1);
#pragma unroll
        for (int m = 0; m < 8; m++)
#pragma unroll
            for (int n = 0; n < 4; n++)
                acc[m][n] = __builtin_amdgcn_mfma_f32_16x16x32_bf16(af[m], bfv[n], acc[m][n], 0, 0, 0);
        __builtin_amdgcn_s_setprio(0);
        SB0; BARR; SB0;                               // all waves done reading buf c
        const int rem = NT - 1 - t;
        if (rem >= 3)      { ISSUE4(t + 3, (t + 3) & 3); SB0; WAITVN(8); }   // t+1 landed; t+2,t+3 in flight
        else if (rem == 2) { WAITVN(4); }                                    // t+1 landed; t+2 in flight
        else if (rem == 1) { WAITVN(0); }                                    // last tile landed
        if (rem >= 1) { SB0; BARR; SB0; }
    }
#undef ISSUE4

    // epilogue: region uniform per 64-col wave strip (all boundaries are x64)
    const int col0w = bn + wc * 64;
    int reg;
    if      (col0w < 512)  reg = 0;
    else if (col0w < 1024) reg = 1;
    else if (col0w < 1536) reg = 2;
    else if (col0w < 2048) reg = 3;
    else if (col0w < 2560) reg = 2;
    else if (col0w < 3072) reg = 1;
    else if (col0w < 3584) reg = 4;
    else if (col0w < 4096) reg = 3;
    else if (col0w < 4352) reg = 5;
    else if (col0w < 5376) reg = 3;
    else                   reg = 2;

    unsigned short* wls = smem + wid * 1152;          // wave-private 16 x pitch72 bf16 (in buf0 area; last K-buffer was 3)
    const int nsub = (reg == 5) ? 2 : 1;
#pragma unroll
    for (int m = 0; m < 8; m++) {
        for (int sub = 0; sub < nsub; sub++) {
#pragma unroll
            for (int n = 0; n < 4; n++)
#pragma unroll
                for (int r = 0; r < 4; r++) {
                    float v = acc[m][n][r];
                    float o;
                    if      (reg == 0) o = tanh_(v);
                    else if (reg == 1) o = sigm_(v);
                    else if (reg == 2) o = silu_(v);
                    else if (reg == 3) o = v;
                    else if (reg == 4) o = sigm_(-v);
                    else {
                        float om = 3.14159265358979f * tanh_(v);
                        o = sub ? __sinf(om) : __cosf(om);
                    }
                    wls[(h * 4 + r) * 72 + n * 16 + fr] = f2b(o);
                }
#pragma unroll
            for (int p = 0; p < 2; p++) {
                int lr = p * 8 + (lane >> 3);
                int lc = (lane & 7) * 8;
                bf16x8 v8 = *(bf16x8*)(wls + lr * 72 + lc);
                int grow = bm + wr * 128 + m * 16 + lr;
                int gcol = bn + wc * 64 + lc;
                if (sub == 0)
                    *(bf16x8*)(proj + (size_t)grow * N + gcol) = v8;
                else
                    *(bf16x8*)(swb + (size_t)grow * HALF_ + (gcol - 4096)) = v8;
            }
        }
    }
}

// ---------------------------------------------------------------- GEMM2 (R6-proven 128x128 2-phase)
#define STAGE(kt_, dA, dB) {          \
    gload16(aP0 + (kt_), (dA));       \
    gload16(aP1 + (kt_), (dA) + 512); \
    gload16(bP0 + (kt_), (dB));       \
    gload16(bP1 + (kt_), (dB) + 512); }

#define COMPUTE(sAr, sBr) {                                                            \
    bf16x8 af[4], bfv[4];                                                              \
    _Pragma("unroll")                                                                  \
    for (int m_ = 0; m_ < 4; m_++)                                                     \
        af[m_] = *(const bf16x8*)((sAr) + (wm + m_ * 16 + fr) * 32 + rsl);             \
    _Pragma("unroll")                                                                  \
    for (int n_ = 0; n_ < 4; n_++)                                                     \
        bfv[n_] = *(const bf16x8*)((sBr) + (wn + n_ * 16 + fr) * 32 + rsl);            \
    _Pragma("unroll")                                                                  \
    for (int m_ = 0; m_ < 4; m_++)                                                     \
        _Pragma("unroll")                                                              \
        for (int n_ = 0; n_ < 4; n_++)                                                 \
            acc[m_][n_] = __builtin_amdgcn_mfma_f32_16x16x32_bf16(af[m_], bfv[n_], acc[m_][n_], 0, 0, 0); }

__global__ __launch_bounds__(256, 3) void gemm_f32out(
    const unsigned short* __restrict__ A,
    const unsigned short* __restrict__ Bt,
    float* __restrict__ outp,
    const int M, const int N, const int K)
{
    __shared__ __align__(16) char smem[32768];   // 2 x (8KB A + 8KB B)
    unsigned short* sA0 = (unsigned short*)smem;
    unsigned short* sB0 = (unsigned short*)(smem + 8192);
    unsigned short* sA1 = (unsigned short*)(smem + 16384);
    unsigned short* sB1 = (unsigned short*)(smem + 24576);
    const int tid  = threadIdx.x;
    const int wid  = tid >> 6;
    const int lane = tid & 63;

    const int flat = blockIdx.y * gridDim.x + blockIdx.x;
    const int xcd  = flat & 7;
    const int ii   = flat >> 3;
    const int bm   = ((xcd << 3) + (ii & 7)) * 128;
    const int bn   = (ii >> 3) * 128;

    const int wm = (wid >> 1) * 64;
    const int wn = (wid & 1) * 64;

    f32x4 acc[4][4];
#pragma unroll
    for (int m = 0; m < 4; m++)
#pragma unroll
        for (int n = 0; n < 4; n++) acc[m][n] = (f32x4){0.f, 0.f, 0.f, 0.f};

    const int r0 = wid * 32 + (lane >> 2);
    const int sl = ((lane & 3) ^ ((r0 >> 1) & 3)) * 8;
    const unsigned short* aP0 = A  + (size_t)(bm + r0)      * K + sl;
    const unsigned short* aP1 = A  + (size_t)(bm + r0 + 16) * K + sl;
    const unsigned short* bP0 = Bt + (size_t)(bn + r0)      * K + sl;
    const unsigned short* bP1 = Bt + (size_t)(bn + r0 + 16) * K + sl;
    unsigned short* wA0 = sA0 + wid * 1024;
    unsigned short* wB0 = sB0 + wid * 1024;
    unsigned short* wA1 = sA1 + wid * 1024;
    unsigned short* wB1 = sB1 + wid * 1024;

    const int fr  = lane & 15;
    const int h   = lane >> 4;
    const int rsl = (h ^ ((fr >> 1) & 3)) * 8;
    const int nt  = K >> 5;

    STAGE(0, wA0, wB0);
    __syncthreads();
    for (int t = 0; t < nt; t += 2) {
        STAGE((t + 1) * 32, wA1, wB1);
        COMPUTE(sA0, sB0);
        __syncthreads();
        if (t + 2 < nt) STAGE((t + 2) * 32, wA0, wB0);
        COMPUTE(sA1, sB1);
        __syncthreads();
    }

    float* wp = (float*)(smem + wid * 4608);
#pragma unroll
    for (int m = 0; m < 4; m++) {
#pragma unroll
        for (int n = 0; n < 4; n++)
#pragma unroll
            for (int r = 0; r < 4; r++)
                wp[(h * 4 + r) * 68 + n * 16 + fr] = acc[m][n][r];
#pragma unroll
        for (int rnd = 0; rnd < 4; rnd++) {
            int lr = rnd * 4 + (lane >> 4);
            int lc = (lane & 15) * 4;
            float4 v = *(float4*)&wp[lr * 68 + lc];
            int grow = bm + wm + m * 16 + lr;
            int gcol = bn + wn + lc;
            *(float4*)&outp[(size_t)grow * N + gcol] = v;
        }
    }
}

// ---------------------------------------------------------------- scan pass 1: chunk summaries
__global__ void scan_pass1(const unsigned short* __restrict__ proj, const unsigned short* __restrict__ swb,
                           float* __restrict__ rsP, float* __restrict__ rsY,
                           float4* __restrict__ ssM, float2* __restrict__ ssY) {
    const int c = blockIdx.x, b = blockIdx.y, z = blockIdx.z, tid = threadIdx.x;
    const int row0 = b * T_ + c * LC_;
    const unsigned short* base = proj + (size_t)row0 * N1_;
    if (z < 2) {
        const int s = z * 256 + tid;
        float P = 1.f, y = 0.f;
#pragma unroll 4
        for (int t = 0; t < LC_; t++) {
            const unsigned short* r = base + (size_t)t * N1_;
            float rf = b2f(r[s]);
            float rg = b2f(r[512 + s]);
            float rc = b2f(r[1024 + s]);
            y = rf * y + rg * rc;
            P *= rf;
        }
        int idx = (b * NCH_ + c) * S_ + s;
        rsP[idx] = P; rsY[idx] = y;
    } else {
        const int p = tid;
        const unsigned short* swr = swb + (size_t)row0 * HALF_;
        float m00 = 1.f, m01 = 0.f, m10 = 0.f, m11 = 1.f, y0 = 0.f, y1 = 0.f;
#pragma unroll 2
        for (int t = 0; t < LC_; t++) {
            const unsigned short* r = base + (size_t)t * N1_;
            float cw  = b2f(r[4096 + p]);
            float sw  = b2f(swr[(size_t)t * HALF_ + p]);
            float de  = b2f(r[3072 + p]);
            float dob = b2f(r[3328 + p]);
            float ge  = b2f(r[2560 + p]);
            float go  = b2f(r[2816 + p]);
            float ce  = b2f(r[2048 + p]);
            float co  = b2f(r[2304 + p]);
            float a = de * cw, bb = -de * sw, cc = dob * sw, dd = dob * cw;
            float ny0 = a * y0 + bb * y1 + ge * ce;
            float ny1 = cc * y0 + dd * y1 + go * co;
            y0 = ny0; y1 = ny1;
            float n00 = a * m00 + bb * m10, n01 = a * m01 + bb * m11;
            float n10 = cc * m00 + dd * m10, n11 = cc * m01 + dd * m11;
            m00 = n00; m01 = n01; m10 = n10; m11 = n11;
        }
        int idx = (b * NCH_ + c) * HALF_ + p;
        ssM[idx] = (float4){m00, m01, m10, m11};
        ssY[idx] = (float2){y0, y1};
    }
}

// ---------------------------------------------------------------- scan pass 2: chunk-start states
__global__ void scan_pass2(const float* __restrict__ rsP, const float* __restrict__ rsY,
                           const float4* __restrict__ ssM, const float2* __restrict__ ssY,
                           const float* __restrict__ read_init, const float* __restrict__ stable_init,
                           float* __restrict__ rsStart, float2* __restrict__ ssStart) {
    int id = blockIdx.x * 256 + threadIdx.x;
    if (id < B_ * S_) {
        int b = id / S_, s = id % S_;
        float st = read_init[s];
        for (int c = 0; c < NCH_; c++) {
            int idx = (b * NCH_ + c) * S_ + s;
            rsStart[idx] = st;
            st = rsP[idx] * st + rsY[idx];
        }
    } else {
        id -= B_ * S_;
        int b = id / HALF_, p = id % HALF_;
        float y0 = stable_init[p], y1 = stable_init[p + HALF_];
        for (int c = 0; c < NCH_; c++) {
            int idx = (b * NCH_ + c) * HALF_ + p;
            ssStart[idx] = (float2){y0, y1};
            float4 m = ssM[idx]; float2 u = ssY[idx];
            float ny0 = m.x * y0 + m.y * y1 + u.x;
            float ny1 = m.z * y0 + m.w * y1 + u.y;
            y0 = ny0; y1 = ny1;
        }
    }
}

// ---------------------------------------------------------------- scan pass 3: recompute + emit G
__global__ void scan_pass3(const unsigned short* __restrict__ proj, const unsigned short* __restrict__ swb,
                           const float* __restrict__ rsStart, const float2* __restrict__ ssStart,
                           const float4* __restrict__ mw, unsigned short* __restrict__ G) {
    const int c = blockIdx.x, b = blockIdx.y, z = blockIdx.z, tid = threadIdx.x;
    const int row0 = b * T_ + c * LC_;
    const unsigned short* base = proj + (size_t)row0 * N1_;
    if (z < 2) {
        const int s = z * 256 + tid;
        float rs = rsStart[(b * NCH_ + c) * S_ + s];
#pragma unroll 4
        for (int t = 0; t < LC_; t++) {
            const size_t row = row0 + t;
            const unsigned short* r = base + (size_t)t * N1_;
            float rf = b2f(r[s]);
            float rg = b2f(r[512 + s]);
            float rc = b2f(r[1024 + s]);
            rs = rf * rs + rg * rc;
            float q  = b2f(r[1536 + s]);
            float zz = q * rs;
            G[row * 2048 + s] = f2b(mw[row].x * silu_(zz));
        }
    } else {
        const int p = tid;
        const unsigned short* swr = swb + (size_t)row0 * HALF_;
        float2 st = ssStart[(b * NCH_ + c) * HALF_ + p];
        float y0 = st.x, y1 = st.y;
#pragma unroll 2
        for (int t = 0; t < LC_; t++) {
            const size_t row = row0 + t;
            const unsigned short* r = base + (size_t)t * N1_;
            float cw  = b2f(r[4096 + p]);
            float sw  = b2f(swr[(size_t)t * HALF_ + p]);
            float de  = b2f(r[3072 + p]);
            float dob = b2f(r[3328 + p]);
            float ge  = b2f(r[2560 + p]);
            float go  = b2f(r[2816 + p]);
            float ce  = b2f(r[2048 + p]);
            float co  = b2f(r[2304 + p]);
            float a = de * cw, bb = -de * sw, cc = dob * sw, dd = dob * cw;
            float ny0 = a * y0 + bb * y1 + ge * ce;
            float ny1 = cc * y0 + dd * y1 + go * co;
            y0 = ny0; y1 = ny1;
            float qe = b2f(r[3584 + p]);
            float qo = b2f(r[3840 + p]);
            float w1v = mw[row].y;
            G[row * 2048 + 512 + p] = f2b(w1v * silu_(qe * y0));
            G[row * 2048 + 768 + p] = f2b(w1v * silu_(qo * y1));
        }
    }
}

// ---------------------------------------------------------------- local branch elementwise
__global__ void local_ew(const unsigned short* __restrict__ proj, const float4* __restrict__ mw,
                         unsigned short* __restrict__ G) {
    int i   = blockIdx.x * 256 + threadIdx.x;
    int row = i >> 7;
    int j   = (i & 127) * 8;
    bf16x8 up = *(const bf16x8*)(proj + (size_t)row * N1_ + 4352 + j);
    bf16x8 gs = *(const bf16x8*)(proj + (size_t)row * N1_ + 5376 + j);
    float m2 = mw[row].z;
    bf16x8 o;
#pragma unroll
    for (int e = 0; e < 8; e++)
        o[e] = (short)f2b(m2 * b2f((unsigned short)up[e]) * b2f((unsigned short)gs[e]));
    *(bf16x8*)(G + (size_t)row * 2048 + 1024 + j) = o;
}

// ================================================================ host
extern "C" void kernel_launch(void* const* d_in, const int* in_sizes, int n_in,
                              void* d_out, int out_size, void* d_ws, size_t ws_size,
                              hipStream_t stream) {
    const float* x       = (const float*)d_in[0];
    const float* W_rf    = (const float*)d_in[1];
    const float* W_ri    = (const float*)d_in[2];
    const float* W_rv    = (const float*)d_in[3];
    const float* W_rq    = (const float*)d_in[4];
    const float* W_ro    = (const float*)d_in[5];
    const float* W_sw    = (const float*)d_in[6];
    const float* W_sg    = (const float*)d_in[7];
    const float* W_som   = (const float*)d_in[8];
    const float* W_sd    = (const float*)d_in[9];
    const float* W_sq    = (const float*)d_in[10];
    const float* W_so    = (const float*)d_in[11];
    const float* W_up    = (const float*)d_in[12];
    const float* W_gate  = (const float*)d_in[13];
    const float* W_down  = (const float*)d_in[14];
    const float* W_mix   = (const float*)d_in[15];
    const float* read_init   = (const float*)d_in[16];
    const float* stable_init = (const float*)d_in[17];

    char* ws = (char*)d_ws;
    size_t off = 0;
    auto alloc = [&](size_t bytes) -> void* {
        void* p = ws + off;
        off = (off + bytes + 255) & ~(size_t)255;
        return p;
    };
    unsigned short* xb   = (unsigned short*)alloc((size_t)BT_ * H_ * 2);
    unsigned short* w1   = (unsigned short*)alloc((size_t)N1_ * K1_ * 2);
    unsigned short* w2   = (unsigned short*)alloc((size_t)N2_ * K2_ * 2);
    unsigned short* proj = (unsigned short*)alloc((size_t)BT_ * N1_ * 2);
    unsigned short* swb  = (unsigned short*)alloc((size_t)BT_ * HALF_ * 2);
    float4*         mw   = (float4*)alloc((size_t)BT_ * 16);
    unsigned short* G    = (unsigned short*)alloc((size_t)BT_ * 2048 * 2);
    float*  rsP     = (float*) alloc((size_t)B_ * NCH_ * S_ * 4);
    float*  rsY     = (float*) alloc((size_t)B_ * NCH_ * S_ * 4);
    float4* ssM     = (float4*)alloc((size_t)B_ * NCH_ * HALF_ * 16);
    float2* ssY     = (float2*)alloc((size_t)B_ * NCH_ * HALF_ * 8);
    float*  rsStart = (float*) alloc((size_t)B_ * NCH_ * S_ * 4);
    float2* ssStart = (float2*)alloc((size_t)B_ * NCH_ * HALF_ * 8);
    if (off > ws_size) return;

    pack_x_kernel<<<(BT_ * H_ / 4) / 256, 256, 0, stream>>>(x, xb);

    TOps ops;
    int i = 0;
    auto add = [&](const float* s, int Kw, int Nw, int n_ofs, int k_ofs, int which) {
        ops.v[i].src = s; ops.v[i].Kw = Kw; ops.v[i].Nw = Nw;
        ops.v[i].n_ofs = n_ofs; ops.v[i].k_ofs = k_ofs; ops.v[i].which = which; i++;
    };
    add(W_rf,  1024,  512,    0,    0, 0);
    add(W_ri,  1024,  512,  512,    0, 0);
    add(W_rv,  1024,  512, 1024,    0, 0);
    add(W_rq,  1024,  512, 1536,    0, 0);
    add(W_sw,  1024,  512, 2048,    0, 0);
    add(W_sg,  1024,  512, 2560,    0, 0);
    add(W_sd,  1024,  512, 3072,    0, 0);
    add(W_sq,  1024,  512, 3584,    0, 0);
    add(W_som, 1024,  256, 4096,    0, 0);
    add(W_up,  1024, 1024, 4352,    0, 0);
    add(W_gate,1024, 1024, 5376,    0, 0);
    add(W_ro,   512, 1024,    0,    0, 1);
    add(W_so,   512, 1024,    0,  512, 1);
    add(W_down,1024, 1024,    0, 1024, 1);
    pack_w_kernel<<<dim3(32, 32, 14), 256, 0, stream>>>(ops, w1, w2);

    mix_kernel<<<BT_ / 4, 256, 0, stream>>>(x, W_mix, mw);

    gemm256_proj<<<dim3(N1_ / 256, BT_ / 256), 512, 0, stream>>>(xb, w1, proj, swb, BT_, N1_, K1_);

    scan_pass1<<<dim3(NCH_, B_, 3), 256, 0, stream>>>(proj, swb, rsP, rsY, ssM, ssY);
    scan_pass2<<<12, 256, 0, stream>>>(rsP, rsY, ssM, ssY, read_init, stable_init, rsStart, ssStart);
    scan_pass3<<<dim3(NCH_, B_, 3), 256, 0, stream>>>(proj, swb, rsStart, ssStart, mw, G);

    local_ew<<<(BT_ * LOC_ / 8) / 256, 256, 0, stream>>>(proj, mw, G);

    gemm_f32out<<<dim3(N2_ / 128, BT_ / 128), 256, 0, stream>>>(G, w2, (float*)d_out, BT_, N2_, K2_);
}

// Round 8
// 313.014 us; speedup vs baseline: 1.0367x; 1.0367x over previous
//
#include <hip/hip_runtime.h>

#define B_    4
#define T_    2048
#define H_    1024
#define S_    512
#define HALF_ 256
#define LOC_  1024
#define BT_   8192          // B*T rows
#define N1_   6400          // proj cols: 8*512 + 256 + 1024 + 1024
#define K1_   1024
#define N2_   1024
#define K2_   2048
#define NCH_  32            // scan chunks
#define LC_   64            // chunk length (T_/NCH_)

typedef __attribute__((ext_vector_type(8))) short  bf16x8;
typedef __attribute__((ext_vector_type(4))) float  f32x4;
typedef __attribute__((ext_vector_type(4))) unsigned short u16x4;

__device__ __forceinline__ float b2f(unsigned short u) {
    union { unsigned i; float f; } v; v.i = ((unsigned)u) << 16; return v.f;
}
__device__ __forceinline__ unsigned short f2b(float f) {
    union { float f; unsigned i; } v; v.f = f;
    unsigned r = v.i + 0x7fffu + ((v.i >> 16) & 1u);
    return (unsigned short)(r >> 16);
}
__device__ __forceinline__ float rcp_(float x) { return __builtin_amdgcn_rcpf(x); }
__device__ __forceinline__ float sigm_(float v) { return rcp_(1.f + __expf(-v)); }
__device__ __forceinline__ float silu_(float v) { return v * rcp_(1.f + __expf(-v)); }
__device__ __forceinline__ float tanh_(float v) { return 1.f - 2.f * rcp_(1.f + __expf(2.f * v)); }

__device__ __forceinline__ void gload16(const void* g, void* l) {
    __builtin_amdgcn_global_load_lds(
        (const __attribute__((address_space(1))) void*)g,
        (__attribute__((address_space(3))) void*)l,
        16, 0, 0);
}

#define SB0 __builtin_amdgcn_sched_barrier(0)
#define BARRF() { asm volatile("" ::: "memory"); __builtin_amdgcn_s_barrier(); asm volatile("" ::: "memory"); }
#define WAITV4 asm volatile("s_waitcnt vmcnt(4)" ::: "memory")
#define WAITV0 asm volatile("s_waitcnt vmcnt(0)" ::: "memory")

// ---------------------------------------------------------------- pack x -> bf16
__global__ void pack_x_kernel(const float* __restrict__ x, unsigned short* __restrict__ xb) {
    int i = blockIdx.x * 256 + threadIdx.x;
    float4 a = ((const float4*)x)[i];
    u16x4 u;
    u.x = f2b(a.x); u.y = f2b(a.y); u.z = f2b(a.z); u.w = f2b(a.w);
    ((u16x4*)xb)[i] = u;
}

// ------------------------------------------------- transpose-pack weights to [n][k] bf16
struct TOp { const float* src; int Kw; int Nw; int n_ofs; int k_ofs; int which; };
struct TOps { TOp v[14]; };

__global__ void pack_w_kernel(TOps ops, unsigned short* __restrict__ w1, unsigned short* __restrict__ w2) {
    TOp op = ops.v[blockIdx.z];
    int kt = blockIdx.x * 32, nt = blockIdx.y * 32;
    if (kt >= op.Kw || nt >= op.Nw) return;
    __shared__ float tile[32][33];
    int tx = threadIdx.x & 31, ty = threadIdx.x >> 5;   // 32 x 8
#pragma unroll
    for (int r = 0; r < 4; r++) {
        int k = kt + ty + r * 8;
        tile[ty + r * 8][tx] = op.src[(size_t)k * op.Nw + nt + tx];
    }
    __syncthreads();
    unsigned short* dst = op.which ? w2 : w1;
    int stride = op.which ? K2_ : K1_;
#pragma unroll
    for (int r = 0; r < 4; r++) {
        int n = nt + ty + r * 8;
        dst[(size_t)(op.n_ofs + n) * stride + op.k_ofs + kt + tx] = f2b(tile[tx][ty + r * 8]);
    }
}

// ---------------------------------------------------------------- mix softmax (x @ W_mix)
__global__ void mix_kernel(const float* __restrict__ x, const float* __restrict__ Wm,
                           float4* __restrict__ mw) {
    int row  = blockIdx.x * 4 + (threadIdx.x >> 6);
    int lane = threadIdx.x & 63;
    const float* xr = x + (size_t)row * H_;
    float s0 = 0.f, s1 = 0.f, s2 = 0.f;
    for (int k = lane; k < H_; k += 64) {
        float xv = xr[k];
        s0 += xv * Wm[k * 3 + 0];
        s1 += xv * Wm[k * 3 + 1];
        s2 += xv * Wm[k * 3 + 2];
    }
#pragma unroll
    for (int off = 32; off; off >>= 1) {
        s0 += __shfl_down(s0, off);
        s1 += __shfl_down(s1, off);
        s2 += __shfl_down(s2, off);
    }
    if (lane == 0) {
        float m = fmaxf(s0, fmaxf(s1, s2));
        float e0 = __expf(s0 - m), e1 = __expf(s1 - m), e2 = __expf(s2 - m);
        float inv = 1.f / (e0 + e1 + e2);
        mw[row] = (float4){ e0 * inv, e1 * inv, e2 * inv, 0.f };
    }
}

// ================================================================ GEMM1: 256x256, BK=64,
// 8 waves (2Mx4N, 128x64 out each), dbuf 128KB, 4 fine phases per K-tile:
//   phase = { ds_read frags ; issue 2 gload_lds ; barrier ; setprio MFMA16 setprio ; [vmcnt(4)] ; barrier }
// LDS layout per buffer: [A kk0 16KB][A kk1 16KB][B kk0 16KB][B kk1 16KB], each [256 rows][32 elem]
// (64B rows -> fragment reads spread 8 bank-quads, no XOR swizzle needed; staging is linear).
__global__ __launch_bounds__(512, 2) void gemm256_proj(
    const unsigned short* __restrict__ A,
    const unsigned short* __restrict__ Bt,
    unsigned short* __restrict__ proj,
    unsigned short* __restrict__ swb,
    const int M, const int N, const int K)
{
    __shared__ __align__(16) unsigned short smem[65536];   // 128 KB
    const int tid  = threadIdx.x;
    const int wid  = tid >> 6;
    const int lane = tid & 63;
    const int wr = wid >> 2;          // 0..1
    const int wc = wid & 3;           // 0..3
    const int fr = lane & 15;
    const int h  = lane >> 4;

    // XCD swizzle (bijective: 800 blocks % 8 == 0)
    const int flat = blockIdx.y * gridDim.x + blockIdx.x;
    const int xcd  = flat & 7;
    const int ii   = flat >> 3;
    const int mpx  = gridDim.y >> 3;
    const int bm   = (xcd * mpx + (ii % mpx)) * 256;
    const int bn   = (ii / mpx) * 256;

    f32x4 acc[8][4];
#pragma unroll
    for (int m = 0; m < 8; m++)
#pragma unroll
        for (int n = 0; n < 4; n++) acc[m][n] = (f32x4){0.f, 0.f, 0.f, 0.f};

    // staging: wave w covers rows [w*32, w*32+32) of A-tile and B-tile; linear 16B/lane
    const int rl = lane >> 2;
    const unsigned short* aRow   = A  + (size_t)(bm + wid * 32 + rl) * K + (lane & 3) * 8;
    const unsigned short* aRow16 = aRow + (size_t)16 * K;
    const unsigned short* bRow   = Bt + (size_t)(bn + wid * 32 + rl) * K + (lane & 3) * 8;
    const unsigned short* bRow16 = bRow + (size_t)16 * K;

    // fragment read offsets (elements) within a kk-half
    const int aOff = (wr * 128 + fr) * 32 + h * 8;
    const int bOff = (wc * 64 + fr) * 32 + h * 8;
    const int NT   = K >> 6;   // 16

#define ISSA2(P, tt, hh) { unsigned short* d = (P) + (hh) * 8192 + wid * 1024;           \
        gload16(aRow   + (size_t)(tt) * 64 + (hh) * 32, d);                              \
        gload16(aRow16 + (size_t)(tt) * 64 + (hh) * 32, d + 512); }
#define ISSB2(P, tt, hh) { unsigned short* d = (P) + 16384 + (hh) * 8192 + wid * 1024;   \
        gload16(bRow   + (size_t)(tt) * 64 + (hh) * 32, d);                              \
        gload16(bRow16 + (size_t)(tt) * 64 + (hh) * 32, d + 512); }
#define MFMA16(mh) {                                                                     \
        __builtin_amdgcn_s_setprio(1);                                                   \
        _Pragma("unroll")                                                                \
        for (int m_ = 0; m_ < 4; m_++)                                                   \
            _Pragma("unroll")                                                            \
            for (int n_ = 0; n_ < 4; n_++)                                               \
                acc[(mh) * 4 + m_][n_] =                                                 \
                    __builtin_amdgcn_mfma_f32_16x16x32_bf16(af[m_], bfv[n_], acc[(mh) * 4 + m_][n_], 0, 0, 0); \
        __builtin_amdgcn_s_setprio(0); }

    // prologue: stage all 4 halves of tile 0 into buf 0, wait first 2 halves
    ISSA2(smem, 0, 0); ISSB2(smem, 0, 0); ISSA2(smem, 0, 1); ISSB2(smem, 0, 1);
    SB0; WAITV4; SB0; BARRF();

    for (int t = 0; t < NT; ++t) {
        const unsigned short* Pc = smem + (t & 1) * 32768;
        unsigned short*       Pn = smem + ((t & 1) ^ 1) * 32768;
        const bool pre = (t + 1 < NT);
        bf16x8 af[4], bfv[4];

        // ---- phase 0: kk0, m 0..3 (+ B kk0 read); issue A-h0(t+1)
#pragma unroll
        for (int n = 0; n < 4; n++) bfv[n] = *(const bf16x8*)(Pc + 16384 + bOff + n * 512);
#pragma unroll
        for (int m = 0; m < 4; m++) af[m] = *(const bf16x8*)(Pc + aOff + m * 512);
        if (pre) ISSA2(Pn, t + 1, 0);
        BARRF();
        MFMA16(0);
        BARRF();

        // ---- phase 1: kk0, m 4..7; issue B-h0(t+1); counted wait for kk1 halves
#pragma unroll
        for (int m = 0; m < 4; m++) af[m] = *(const bf16x8*)(Pc + aOff + 2048 + m * 512);
        if (pre) ISSB2(Pn, t + 1, 0);
        BARRF();
        MFMA16(1);
        if (pre) { SB0; WAITV4; SB0; } else { SB0; WAITV0; SB0; }
        BARRF();

        // ---- phase 2: kk1, m 0..3 (+ B kk1 read); issue A-h1(t+1)
#pragma unroll
        for (int n = 0; n < 4; n++) bfv[n] = *(const bf16x8*)(Pc + 24576 + bOff + n * 512);
#pragma unroll
        for (int m = 0; m < 4; m++) af[m] = *(const bf16x8*)(Pc + 8192 + aOff + m * 512);
        if (pre) ISSA2(Pn, t + 1, 1);
        BARRF();
        MFMA16(0);
        BARRF();

        // ---- phase 3: kk1, m 4..7; issue B-h1(t+1); counted wait for next tile's kk0 halves
#pragma unroll
        for (int m = 0; m < 4; m++) af[m] = *(const bf16x8*)(Pc + 8192 + aOff + 2048 + m * 512);
        if (pre) ISSB2(Pn, t + 1, 1);
        BARRF();
        MFMA16(1);
        if (pre) { SB0; WAITV4; SB0; }
        BARRF();
    }
#undef ISSA2
#undef ISSB2
#undef MFMA16

    // epilogue: region uniform per 64-col wave strip (all boundaries are x64)
    const int col0w = bn + wc * 64;
    int reg;
    if      (col0w < 512)  reg = 0;
    else if (col0w < 1024) reg = 1;
    else if (col0w < 1536) reg = 2;
    else if (col0w < 2048) reg = 3;
    else if (col0w < 2560) reg = 2;
    else if (col0w < 3072) reg = 1;
    else if (col0w < 3584) reg = 4;
    else if (col0w < 4096) reg = 3;
    else if (col0w < 4352) reg = 5;
    else if (col0w < 5376) reg = 3;
    else                   reg = 2;

    unsigned short* wls = smem + wid * 1152;          // wave-private 16 x pitch72 bf16
    const int nsub = (reg == 5) ? 2 : 1;
#pragma unroll
    for (int m = 0; m < 8; m++) {
        for (int sub = 0; sub < nsub; sub++) {
#pragma unroll
            for (int n = 0; n < 4; n++)
#pragma unroll
                for (int r = 0; r < 4; r++) {
                    float v = acc[m][n][r];
                    float o;
                    if      (reg == 0) o = tanh_(v);
                    else if (reg == 1) o = sigm_(v);
                    else if (reg == 2) o = silu_(v);
                    else if (reg == 3) o = v;
                    else if (reg == 4) o = sigm_(-v);
                    else {
                        float om = 3.14159265358979f * tanh_(v);
                        o = sub ? __sinf(om) : __cosf(om);
                    }
                    wls[(h * 4 + r) * 72 + n * 16 + fr] = f2b(o);
                }
#pragma unroll
            for (int p = 0; p < 2; p++) {
                int lr = p * 8 + (lane >> 3);
                int lc = (lane & 7) * 8;
                bf16x8 v8 = *(bf16x8*)(wls + lr * 72 + lc);
                int grow = bm + wr * 128 + m * 16 + lr;
                int gcol = bn + wc * 64 + lc;
                if (sub == 0)
                    *(bf16x8*)(proj + (size_t)grow * N + gcol) = v8;
                else
                    *(bf16x8*)(swb + (size_t)grow * HALF_ + (gcol - 4096)) = v8;
            }
        }
    }
}

// ---------------------------------------------------------------- GEMM2 (R6-proven 128x128 2-phase)
#define STAGE(kt_, dA, dB) {          \
    gload16(aP0 + (kt_), (dA));       \
    gload16(aP1 + (kt_), (dA) + 512); \
    gload16(bP0 + (kt_), (dB));       \
    gload16(bP1 + (kt_), (dB) + 512); }

#define COMPUTE(sAr, sBr) {                                                            \
    bf16x8 af[4], bfv[4];                                                              \
    _Pragma("unroll")                                                                  \
    for (int m_ = 0; m_ < 4; m_++)                                                     \
        af[m_] = *(const bf16x8*)((sAr) + (wm + m_ * 16 + fr) * 32 + rsl);             \
    _Pragma("unroll")                                                                  \
    for (int n_ = 0; n_ < 4; n_++)                                                     \
        bfv[n_] = *(const bf16x8*)((sBr) + (wn + n_ * 16 + fr) * 32 + rsl);            \
    _Pragma("unroll")                                                                  \
    for (int m_ = 0; m_ < 4; m_++)                                                     \
        _Pragma("unroll")                                                              \
        for (int n_ = 0; n_ < 4; n_++)                                                 \
            acc[m_][n_] = __builtin_amdgcn_mfma_f32_16x16x32_bf16(af[m_], bfv[n_], acc[m_][n_], 0, 0, 0); }

__global__ __launch_bounds__(256, 3) void gemm_f32out(
    const unsigned short* __restrict__ A,
    const unsigned short* __restrict__ Bt,
    float* __restrict__ outp,
    const int M, const int N, const int K)
{
    __shared__ __align__(16) char smem[32768];   // 2 x (8KB A + 8KB B)
    unsigned short* sA0 = (unsigned short*)smem;
    unsigned short* sB0 = (unsigned short*)(smem + 8192);
    unsigned short* sA1 = (unsigned short*)(smem + 16384);
    unsigned short* sB1 = (unsigned short*)(smem + 24576);
    const int tid  = threadIdx.x;
    const int wid  = tid >> 6;
    const int lane = tid & 63;

    const int flat = blockIdx.y * gridDim.x + blockIdx.x;
    const int xcd  = flat & 7;
    const int ii   = flat >> 3;
    const int bm   = ((xcd << 3) + (ii & 7)) * 128;
    const int bn   = (ii >> 3) * 128;

    const int wm = (wid >> 1) * 64;
    const int wn = (wid & 1) * 64;

    f32x4 acc[4][4];
#pragma unroll
    for (int m = 0; m < 4; m++)
#pragma unroll
        for (int n = 0; n < 4; n++) acc[m][n] = (f32x4){0.f, 0.f, 0.f, 0.f};

    const int r0 = wid * 32 + (lane >> 2);
    const int sl = ((lane & 3) ^ ((r0 >> 1) & 3)) * 8;
    const unsigned short* aP0 = A  + (size_t)(bm + r0)      * K + sl;
    const unsigned short* aP1 = A  + (size_t)(bm + r0 + 16) * K + sl;
    const unsigned short* bP0 = Bt + (size_t)(bn + r0)      * K + sl;
    const unsigned short* bP1 = Bt + (size_t)(bn + r0 + 16) * K + sl;
    unsigned short* wA0 = sA0 + wid * 1024;
    unsigned short* wB0 = sB0 + wid * 1024;
    unsigned short* wA1 = sA1 + wid * 1024;
    unsigned short* wB1 = sB1 + wid * 1024;

    const int fr  = lane & 15;
    const int h   = lane >> 4;
    const int rsl = (h ^ ((fr >> 1) & 3)) * 8;
    const int nt  = K >> 5;

    STAGE(0, wA0, wB0);
    __syncthreads();
    for (int t = 0; t < nt; t += 2) {
        STAGE((t + 1) * 32, wA1, wB1);
        COMPUTE(sA0, sB0);
        __syncthreads();
        if (t + 2 < nt) STAGE((t + 2) * 32, wA0, wB0);
        COMPUTE(sA1, sB1);
        __syncthreads();
    }

    float* wp = (float*)(smem + wid * 4608);
#pragma unroll
    for (int m = 0; m < 4; m++) {
#pragma unroll
        for (int n = 0; n < 4; n++)
#pragma unroll
            for (int r = 0; r < 4; r++)
                wp[(h * 4 + r) * 68 + n * 16 + fr] = acc[m][n][r];
#pragma unroll
        for (int rnd = 0; rnd < 4; rnd++) {
            int lr = rnd * 4 + (lane >> 4);
            int lc = (lane & 15) * 4;
            float4 v = *(float4*)&wp[lr * 68 + lc];
            int grow = bm + wm + m * 16 + lr;
            int gcol = bn + wn + lc;
            *(float4*)&outp[(size_t)grow * N + gcol] = v;
        }
    }
}

// ---------------------------------------------------------------- scan pass 1: chunk summaries
__global__ void scan_pass1(const unsigned short* __restrict__ proj, const unsigned short* __restrict__ swb,
                           float* __restrict__ rsP, float* __restrict__ rsY,
                           float4* __restrict__ ssM, float2* __restrict__ ssY) {
    const int c = blockIdx.x, b = blockIdx.y, z = blockIdx.z, tid = threadIdx.x;
    const int row0 = b * T_ + c * LC_;
    const unsigned short* base = proj + (size_t)row0 * N1_;
    if (z < 2) {
        const int s = z * 256 + tid;
        float P = 1.f, y = 0.f;
#pragma unroll 4
        for (int t = 0; t < LC_; t++) {
            const unsigned short* r = base + (size_t)t * N1_;
            float rf = b2f(r[s]);
            float rg = b2f(r[512 + s]);
            float rc = b2f(r[1024 + s]);
            y = rf * y + rg * rc;
            P *= rf;
        }
        int idx = (b * NCH_ + c) * S_ + s;
        rsP[idx] = P; rsY[idx] = y;
    } else {
        const int p = tid;
        const unsigned short* swr = swb + (size_t)row0 * HALF_;
        float m00 = 1.f, m01 = 0.f, m10 = 0.f, m11 = 1.f, y0 = 0.f, y1 = 0.f;
#pragma unroll 2
        for (int t = 0; t < LC_; t++) {
            const unsigned short* r = base + (size_t)t * N1_;
            float cw  = b2f(r[4096 + p]);
            float sw  = b2f(swr[(size_t)t * HALF_ + p]);
            float de  = b2f(r[3072 + p]);
            float dob = b2f(r[3328 + p]);
            float ge  = b2f(r[2560 + p]);
            float go  = b2f(r[2816 + p]);
            float ce  = b2f(r[2048 + p]);
            float co  = b2f(r[2304 + p]);
            float a = de * cw, bb = -de * sw, cc = dob * sw, dd = dob * cw;
            float ny0 = a * y0 + bb * y1 + ge * ce;
            float ny1 = cc * y0 + dd * y1 + go * co;
            y0 = ny0; y1 = ny1;
            float n00 = a * m00 + bb * m10, n01 = a * m01 + bb * m11;
            float n10 = cc * m00 + dd * m10, n11 = cc * m01 + dd * m11;
            m00 = n00; m01 = n01; m10 = n10; m11 = n11;
        }
        int idx = (b * NCH_ + c) * HALF_ + p;
        ssM[idx] = (float4){m00, m01, m10, m11};
        ssY[idx] = (float2){y0, y1};
    }
}

// ---------------------------------------------------------------- scan pass 2: chunk-start states
__global__ void scan_pass2(const float* __restrict__ rsP, const float* __restrict__ rsY,
                           const float4* __restrict__ ssM, const float2* __restrict__ ssY,
                           const float* __restrict__ read_init, const float* __restrict__ stable_init,
                           float* __restrict__ rsStart, float2* __restrict__ ssStart) {
    int id = blockIdx.x * 256 + threadIdx.x;
    if (id < B_ * S_) {
        int b = id / S_, s = id % S_;
        float st = read_init[s];
        for (int c = 0; c < NCH_; c++) {
            int idx = (b * NCH_ + c) * S_ + s;
            rsStart[idx] = st;
            st = rsP[idx] * st + rsY[idx];
        }
    } else {
        id -= B_ * S_;
        int b = id / HALF_, p = id % HALF_;
        float y0 = stable_init[p], y1 = stable_init[p + HALF_];
        for (int c = 0; c < NCH_; c++) {
            int idx = (b * NCH_ + c) * HALF_ + p;
            ssStart[idx] = (float2){y0, y1};
            float4 m = ssM[idx]; float2 u = ssY[idx];
            float ny0 = m.x * y0 + m.y * y1 + u.x;
            float ny1 = m.z * y0 + m.w * y1 + u.y;
            y0 = ny0; y1 = ny1;
        }
    }
}

// ---------------------------------------------------------------- scan pass 3: recompute + emit G
__global__ void scan_pass3(const unsigned short* __restrict__ proj, const unsigned short* __restrict__ swb,
                           const float* __restrict__ rsStart, const float2* __restrict__ ssStart,
                           const float4* __restrict__ mw, unsigned short* __restrict__ G) {
    const int c = blockIdx.x, b = blockIdx.y, z = blockIdx.z, tid = threadIdx.x;
    const int row0 = b * T_ + c * LC_;
    const unsigned short* base = proj + (size_t)row0 * N1_;
    if (z < 2) {
        const int s = z * 256 + tid;
        float rs = rsStart[(b * NCH_ + c) * S_ + s];
#pragma unroll 4
        for (int t = 0; t < LC_; t++) {
            const size_t row = row0 + t;
            const unsigned short* r = base + (size_t)t * N1_;
            float rf = b2f(r[s]);
            float rg = b2f(r[512 + s]);
            float rc = b2f(r[1024 + s]);
            rs = rf * rs + rg * rc;
            float q  = b2f(r[1536 + s]);
            float zz = q * rs;
            G[row * 2048 + s] = f2b(mw[row].x * silu_(zz));
        }
    } else {
        const int p = tid;
        const unsigned short* swr = swb + (size_t)row0 * HALF_;
        float2 st = ssStart[(b * NCH_ + c) * HALF_ + p];
        float y0 = st.x, y1 = st.y;
#pragma unroll 2
        for (int t = 0; t < LC_; t++) {
            const size_t row = row0 + t;
            const unsigned short* r = base + (size_t)t * N1_;
            float cw  = b2f(r[4096 + p]);
            float sw  = b2f(swr[(size_t)t * HALF_ + p]);
            float de  = b2f(r[3072 + p]);
            float dob = b2f(r[3328 + p]);
            float ge  = b2f(r[2560 + p]);
            float go  = b2f(r[2816 + p]);
            float ce  = b2f(r[2048 + p]);
            float co  = b2f(r[2304 + p]);
            float a = de * cw, bb = -de * sw, cc = dob * sw, dd = dob * cw;
            float ny0 = a * y0 + bb * y1 + ge * ce;
            float ny1 = cc * y0 + dd * y1 + go * co;
            y0 = ny0; y1 = ny1;
            float qe = b2f(r[3584 + p]);
            float qo = b2f(r[3840 + p]);
            float w1v = mw[row].y;
            G[row * 2048 + 512 + p] = f2b(w1v * silu_(qe * y0));
            G[row * 2048 + 768 + p] = f2b(w1v * silu_(qo * y1));
        }
    }
}

// ---------------------------------------------------------------- local branch elementwise
__global__ void local_ew(const unsigned short* __restrict__ proj, const float4* __restrict__ mw,
                         unsigned short* __restrict__ G) {
    int i   = blockIdx.x * 256 + threadIdx.x;
    int row = i >> 7;
    int j   = (i & 127) * 8;
    bf16x8 up = *(const bf16x8*)(proj + (size_t)row * N1_ + 4352 + j);
    bf16x8 gs = *(const bf16x8*)(proj + (size_t)row * N1_ + 5376 + j);
    float m2 = mw[row].z;
    bf16x8 o;
#pragma unroll
    for (int e = 0; e < 8; e++)
        o[e] = (short)f2b(m2 * b2f((unsigned short)up[e]) * b2f((unsigned short)gs[e]));
    *(bf16x8*)(G + (size_t)row * 2048 + 1024 + j) = o;
}

// ================================================================ host
extern "C" void kernel_launch(void* const* d_in, const int* in_sizes, int n_in,
                              void* d_out, int out_size, void* d_ws, size_t ws_size,
                              hipStream_t stream) {
    const float* x       = (const float*)d_in[0];
    const float* W_rf    = (const float*)d_in[1];
    const float* W_ri    = (const float*)d_in[2];
    const float* W_rv    = (const float*)d_in[3];
    const float* W_rq    = (const float*)d_in[4];
    const float* W_ro    = (const float*)d_in[5];
    const float* W_sw    = (const float*)d_in[6];
    const float* W_sg    = (const float*)d_in[7];
    const float* W_som   = (const float*)d_in[8];
    const float* W_sd    = (const float*)d_in[9];
    const float* W_sq    = (const float*)d_in[10];
    const float* W_so    = (const float*)d_in[11];
    const float* W_up    = (const float*)d_in[12];
    const float* W_gate  = (const float*)d_in[13];
    const float* W_down  = (const float*)d_in[14];
    const float* W_mix   = (const float*)d_in[15];
    const float* read_init   = (const float*)d_in[16];
    const float* stable_init = (const float*)d_in[17];

    char* ws = (char*)d_ws;
    size_t off = 0;
    auto alloc = [&](size_t bytes) -> void* {
        void* p = ws + off;
        off = (off + bytes + 255) & ~(size_t)255;
        return p;
    };
    unsigned short* xb   = (unsigned short*)alloc((size_t)BT_ * H_ * 2);
    unsigned short* w1   = (unsigned short*)alloc((size_t)N1_ * K1_ * 2);
    unsigned short* w2   = (unsigned short*)alloc((size_t)N2_ * K2_ * 2);
    unsigned short* proj = (unsigned short*)alloc((size_t)BT_ * N1_ * 2);
    unsigned short* swb  = (unsigned short*)alloc((size_t)BT_ * HALF_ * 2);
    float4*         mw   = (float4*)alloc((size_t)BT_ * 16);
    unsigned short* G    = (unsigned short*)alloc((size_t)BT_ * 2048 * 2);
    float*  rsP     = (float*) alloc((size_t)B_ * NCH_ * S_ * 4);
    float*  rsY     = (float*) alloc((size_t)B_ * NCH_ * S_ * 4);
    float4* ssM     = (float4*)alloc((size_t)B_ * NCH_ * HALF_ * 16);
    float2* ssY     = (float2*)alloc((size_t)B_ * NCH_ * HALF_ * 8);
    float*  rsStart = (float*) alloc((size_t)B_ * NCH_ * S_ * 4);
    float2* ssStart = (float2*)alloc((size_t)B_ * NCH_ * HALF_ * 8);
    if (off > ws_size) return;

    pack_x_kernel<<<(BT_ * H_ / 4) / 256, 256, 0, stream>>>(x, xb);

    TOps ops;
    int i = 0;
    auto add = [&](const float* s, int Kw, int Nw, int n_ofs, int k_ofs, int which) {
        ops.v[i].src = s; ops.v[i].Kw = Kw; ops.v[i].Nw = Nw;
        ops.v[i].n_ofs = n_ofs; ops.v[i].k_ofs = k_ofs; ops.v[i].which = which; i++;
    };
    add(W_rf,  1024,  512,    0,    0, 0);
    add(W_ri,  1024,  512,  512,    0, 0);
    add(W_rv,  1024,  512, 1024,    0, 0);
    add(W_rq,  1024,  512, 1536,    0, 0);
    add(W_sw,  1024,  512, 2048,    0, 0);
    add(W_sg,  1024,  512, 2560,    0, 0);
    add(W_sd,  1024,  512, 3072,    0, 0);
    add(W_sq,  1024,  512, 3584,    0, 0);
    add(W_som, 1024,  256, 4096,    0, 0);
    add(W_up,  1024, 1024, 4352,    0, 0);
    add(W_gate,1024, 1024, 5376,    0, 0);
    add(W_ro,   512, 1024,    0,    0, 1);
    add(W_so,   512, 1024,    0,  512, 1);
    add(W_down,1024, 1024,    0, 1024, 1);
    pack_w_kernel<<<dim3(32, 32, 14), 256, 0, stream>>>(ops, w1, w2);

    mix_kernel<<<BT_ / 4, 256, 0, stream>>>(x, W_mix, mw);

    gemm256_proj<<<dim3(N1_ / 256, BT_ / 256), 512, 0, stream>>>(xb, w1, proj, swb, BT_, N1_, K1_);

    scan_pass1<<<dim3(NCH_, B_, 3), 256, 0, stream>>>(proj, swb, rsP, rsY, ssM, ssY);
    scan_pass2<<<12, 256, 0, stream>>>(rsP, rsY, ssM, ssY, read_init, stable_init, rsStart, ssStart);
    scan_pass3<<<dim3(NCH_, B_, 3), 256, 0, stream>>>(proj, swb, rsStart, ssStart, mw, G);

    local_ew<<<(BT_ * LOC_ / 8) / 256, 256, 0, stream>>>(proj, mw, G);

    gemm_f32out<<<dim3(N2_ / 128, BT_ / 128), 256, 0, stream>>>(G, w2, (float*)d_out, BT_, N2_, K2_);
}

// Round 9
// 306.487 us; speedup vs baseline: 1.0588x; 1.0213x over previous
//
#include <hip/hip_runtime.h>

#define B_    4
#define T_    2048
#define H_    1024
#define S_    512
#define HALF_ 256
#define LOC_  1024
#define BT_   8192          // B*T rows
#define N1_   6400          // proj cols: 8*512 + 256 + 1024 + 1024
#define K1_   1024
#define N2_   1024
#define K2_   2048
#define NCH_  32            // scan chunks
#define LC_   64            // chunk length (T_/NCH_)

typedef __attribute__((ext_vector_type(8))) short  bf16x8;
typedef __attribute__((ext_vector_type(4))) float  f32x4;
typedef __attribute__((ext_vector_type(4))) unsigned short u16x4;

__device__ __forceinline__ float b2f(unsigned short u) {
    union { unsigned i; float f; } v; v.i = ((unsigned)u) << 16; return v.f;
}
__device__ __forceinline__ unsigned short f2b(float f) {
    union { float f; unsigned i; } v; v.f = f;
    unsigned r = v.i + 0x7fffu + ((v.i >> 16) & 1u);
    return (unsigned short)(r >> 16);
}
__device__ __forceinline__ float rcp_(float x) { return __builtin_amdgcn_rcpf(x); }
__device__ __forceinline__ float sigm_(float v) { return rcp_(1.f + __expf(-v)); }
__device__ __forceinline__ float silu_(float v) { return v * rcp_(1.f + __expf(-v)); }
__device__ __forceinline__ float tanh_(float v) { return 1.f - 2.f * rcp_(1.f + __expf(2.f * v)); }

__device__ __forceinline__ void gload16(const void* g, void* l) {
    __builtin_amdgcn_global_load_lds(
        (const __attribute__((address_space(1))) void*)g,
        (__attribute__((address_space(3))) void*)l,
        16, 0, 0);
}

// ---------------------------------------------------------------- pack x -> bf16
__global__ void pack_x_kernel(const float* __restrict__ x, unsigned short* __restrict__ xb) {
    int i = blockIdx.x * 256 + threadIdx.x;
    float4 a = ((const float4*)x)[i];
    u16x4 u;
    u.x = f2b(a.x); u.y = f2b(a.y); u.z = f2b(a.z); u.w = f2b(a.w);
    ((u16x4*)xb)[i] = u;
}

// ------------------------------------------------- transpose-pack weights to [n][k] bf16
struct TOp { const float* src; int Kw; int Nw; int n_ofs; int k_ofs; int which; };
struct TOps { TOp v[14]; };

__global__ void pack_w_kernel(TOps ops, unsigned short* __restrict__ w1, unsigned short* __restrict__ w2) {
    TOp op = ops.v[blockIdx.z];
    int kt = blockIdx.x * 32, nt = blockIdx.y * 32;
    if (kt >= op.Kw || nt >= op.Nw) return;
    __shared__ float tile[32][33];
    int tx = threadIdx.x & 31, ty = threadIdx.x >> 5;   // 32 x 8
#pragma unroll
    for (int r = 0; r < 4; r++) {
        int k = kt + ty + r * 8;
        tile[ty + r * 8][tx] = op.src[(size_t)k * op.Nw + nt + tx];
    }
    __syncthreads();
    unsigned short* dst = op.which ? w2 : w1;
    int stride = op.which ? K2_ : K1_;
#pragma unroll
    for (int r = 0; r < 4; r++) {
        int n = nt + ty + r * 8;
        dst[(size_t)(op.n_ofs + n) * stride + op.k_ofs + kt + tx] = f2b(tile[tx][ty + r * 8]);
    }
}

// ---------------------------------------------------------------- mix softmax (x @ W_mix)
__global__ void mix_kernel(const float* __restrict__ x, const float* __restrict__ Wm,
                           float4* __restrict__ mw) {
    int row  = blockIdx.x * 4 + (threadIdx.x >> 6);
    int lane = threadIdx.x & 63;
    const float* xr = x + (size_t)row * H_;
    float s0 = 0.f, s1 = 0.f, s2 = 0.f;
    for (int k = lane; k < H_; k += 64) {
        float xv = xr[k];
        s0 += xv * Wm[k * 3 + 0];
        s1 += xv * Wm[k * 3 + 1];
        s2 += xv * Wm[k * 3 + 2];
    }
#pragma unroll
    for (int off = 32; off; off >>= 1) {
        s0 += __shfl_down(s0, off);
        s1 += __shfl_down(s1, off);
        s2 += __shfl_down(s2, off);
    }
    if (lane == 0) {
        float m = fmaxf(s0, fmaxf(s1, s2));
        float e0 = __expf(s0 - m), e1 = __expf(s1 - m), e2 = __expf(s2 - m);
        float inv = 1.f / (e0 + e1 + e2);
        mw[row] = (float4){ e0 * inv, e1 * inv, e2 * inv, 0.f };
    }
}

// ================================================================ GEMM1: 256x256, BK=32,
// 8 waves (2Mx4N, 128x64 out each), 64KB double-buffered LDS, R6-proven syncthreads
// stage-ahead loop, R6-proven bank swizzle (slot ^ (row>>1)&3), XCD swizzle,
// wave-private vectorized activation epilogue.
__global__ __launch_bounds__(512, 2) void gemm256_proj(
    const unsigned short* __restrict__ A,
    const unsigned short* __restrict__ Bt,
    unsigned short* __restrict__ proj,
    unsigned short* __restrict__ swb,
    const int M, const int N, const int K)
{
    __shared__ __align__(16) unsigned short smem[32768];   // 64 KB: 2 x (A 8192 + B 8192 elems)
    const int tid  = threadIdx.x;
    const int wid  = tid >> 6;
    const int lane = tid & 63;
    const int wr = wid >> 2;          // 0..1
    const int wc = wid & 3;           // 0..3
    const int fr = lane & 15;
    const int h  = lane >> 4;

    // XCD swizzle (bijective: 800 blocks % 8 == 0)
    const int flat = blockIdx.y * gridDim.x + blockIdx.x;
    const int xcd  = flat & 7;
    const int ii   = flat >> 3;
    const int mpx  = gridDim.y >> 3;                  // 4 m-blocks per XCD
    const int bm   = (xcd * mpx + (ii % mpx)) * 256;
    const int bn   = (ii / mpx) * 256;

    f32x4 acc[8][4];
#pragma unroll
    for (int m = 0; m < 8; m++)
#pragma unroll
        for (int n = 0; n < 4; n++) acc[m][n] = (f32x4){0.f, 0.f, 0.f, 0.f};

    // staging: wave w stages rows {w*16+rl, +128} of A and B tiles; source pre-swizzled
    const int rl4 = lane >> 2;                        // 0..15
    const int sq  = (rl4 >> 1) & 3;                   // swizzle class of staged row
    const int sw  = ((lane & 3) ^ sq) * 8;
    const unsigned short* aR0 = A  + (size_t)(bm + wid * 16 + rl4) * K + sw;
    const unsigned short* aR1 = aR0 + (size_t)128 * K;
    const unsigned short* bR0 = Bt + (size_t)(bn + wid * 16 + rl4) * K + sw;
    const unsigned short* bR1 = bR0 + (size_t)128 * K;

    unsigned short* const buf0 = smem;
    unsigned short* const buf1 = smem + 16384;

#define STG256(kt_, P) {                              \
        gload16(aR0 + (kt_), (P) + wid * 512);        \
        gload16(aR1 + (kt_), (P) + 4096  + wid * 512);\
        gload16(bR0 + (kt_), (P) + 8192  + wid * 512);\
        gload16(bR1 + (kt_), (P) + 12288 + wid * 512); }

    // fragment read: logical half h of row r is at physical slot h^((r>>1)&3); (r>>1)&3 == (fr>>1)&3
    const int rsw = (h ^ ((fr >> 1) & 3)) * 8;

#define CMP256(P) {                                                                     \
        const unsigned short* bufA = (P);                                               \
        const unsigned short* bufB = (P) + 8192;                                        \
        bf16x8 af[8], bfv[4];                                                           \
        _Pragma("unroll")                                                               \
        for (int n_ = 0; n_ < 4; n_++)                                                  \
            bfv[n_] = *(const bf16x8*)(bufB + (wc * 64 + n_ * 16 + fr) * 32 + rsw);     \
        _Pragma("unroll")                                                               \
        for (int m_ = 0; m_ < 8; m_++)                                                  \
            af[m_] = *(const bf16x8*)(bufA + (wr * 128 + m_ * 16 + fr) * 32 + rsw);     \
        _Pragma("unroll")                                                               \
        for (int m_ = 0; m_ < 8; m_++)                                                  \
            _Pragma("unroll")                                                           \
            for (int n_ = 0; n_ < 4; n_++)                                              \
                acc[m_][n_] = __builtin_amdgcn_mfma_f32_16x16x32_bf16(af[m_], bfv[n_], acc[m_][n_], 0, 0, 0); }

    const int NT = K >> 5;                            // 32 (even)
    STG256(0, buf0);
    __syncthreads();
    for (int t = 0; t < NT; t += 2) {
        STG256((t + 1) * 32, buf1);                   // prefetch flies during compute of buf0
        CMP256(buf0);
        __syncthreads();
        if (t + 2 < NT) STG256((t + 2) * 32, buf0);
        CMP256(buf1);
        __syncthreads();
    }
#undef STG256
#undef CMP256

    // epilogue: region uniform per 64-col wave strip (all boundaries are x64)
    const int col0w = bn + wc * 64;
    int reg;
    if      (col0w < 512)  reg = 0;
    else if (col0w < 1024) reg = 1;
    else if (col0w < 1536) reg = 2;
    else if (col0w < 2048) reg = 3;
    else if (col0w < 2560) reg = 2;
    else if (col0w < 3072) reg = 1;
    else if (col0w < 3584) reg = 4;
    else if (col0w < 4096) reg = 3;
    else if (col0w < 4352) reg = 5;
    else if (col0w < 5376) reg = 3;
    else                   reg = 2;

    unsigned short* wls = smem + wid * 1152;          // wave-private 16 x pitch72 bf16
    const int nsub = (reg == 5) ? 2 : 1;
#pragma unroll
    for (int m = 0; m < 8; m++) {
        for (int sub = 0; sub < nsub; sub++) {
#pragma unroll
            for (int n = 0; n < 4; n++)
#pragma unroll
                for (int r = 0; r < 4; r++) {
                    float v = acc[m][n][r];
                    float o;
                    if      (reg == 0) o = tanh_(v);
                    else if (reg == 1) o = sigm_(v);
                    else if (reg == 2) o = silu_(v);
                    else if (reg == 3) o = v;
                    else if (reg == 4) o = sigm_(-v);
                    else {
                        float om = 3.14159265358979f * tanh_(v);
                        o = sub ? __sinf(om) : __cosf(om);
                    }
                    wls[(h * 4 + r) * 72 + n * 16 + fr] = f2b(o);
                }
#pragma unroll
            for (int p = 0; p < 2; p++) {
                int lr = p * 8 + (lane >> 3);
                int lc = (lane & 7) * 8;
                bf16x8 v8 = *(bf16x8*)(wls + lr * 72 + lc);
                int grow = bm + wr * 128 + m * 16 + lr;
                int gcol = bn + wc * 64 + lc;
                if (sub == 0)
                    *(bf16x8*)(proj + (size_t)grow * N + gcol) = v8;
                else
                    *(bf16x8*)(swb + (size_t)grow * HALF_ + (gcol - 4096)) = v8;
            }
        }
    }
}

// ---------------------------------------------------------------- GEMM2 (R6-proven 128x128 2-phase)
#define STAGE(kt_, dA, dB) {          \
    gload16(aP0 + (kt_), (dA));       \
    gload16(aP1 + (kt_), (dA) + 512); \
    gload16(bP0 + (kt_), (dB));       \
    gload16(bP1 + (kt_), (dB) + 512); }

#define COMPUTE(sAr, sBr) {                                                            \
    bf16x8 af[4], bfv[4];                                                              \
    _Pragma("unroll")                                                                  \
    for (int m_ = 0; m_ < 4; m_++)                                                     \
        af[m_] = *(const bf16x8*)((sAr) + (wm + m_ * 16 + fr) * 32 + rsl);             \
    _Pragma("unroll")                                                                  \
    for (int n_ = 0; n_ < 4; n_++)                                                     \
        bfv[n_] = *(const bf16x8*)((sBr) + (wn + n_ * 16 + fr) * 32 + rsl);            \
    _Pragma("unroll")                                                                  \
    for (int m_ = 0; m_ < 4; m_++)                                                     \
        _Pragma("unroll")                                                              \
        for (int n_ = 0; n_ < 4; n_++)                                                 \
            acc[m_][n_] = __builtin_amdgcn_mfma_f32_16x16x32_bf16(af[m_], bfv[n_], acc[m_][n_], 0, 0, 0); }

__global__ __launch_bounds__(256, 3) void gemm_f32out(
    const unsigned short* __restrict__ A,
    const unsigned short* __restrict__ Bt,
    float* __restrict__ outp,
    const int M, const int N, const int K)
{
    __shared__ __align__(16) char smem[32768];   // 2 x (8KB A + 8KB B)
    unsigned short* sA0 = (unsigned short*)smem;
    unsigned short* sB0 = (unsigned short*)(smem + 8192);
    unsigned short* sA1 = (unsigned short*)(smem + 16384);
    unsigned short* sB1 = (unsigned short*)(smem + 24576);
    const int tid  = threadIdx.x;
    const int wid  = tid >> 6;
    const int lane = tid & 63;

    const int flat = blockIdx.y * gridDim.x + blockIdx.x;
    const int xcd  = flat & 7;
    const int ii   = flat >> 3;
    const int bm   = ((xcd << 3) + (ii & 7)) * 128;
    const int bn   = (ii >> 3) * 128;

    const int wm = (wid >> 1) * 64;
    const int wn = (wid & 1) * 64;

    f32x4 acc[4][4];
#pragma unroll
    for (int m = 0; m < 4; m++)
#pragma unroll
        for (int n = 0; n < 4; n++) acc[m][n] = (f32x4){0.f, 0.f, 0.f, 0.f};

    const int r0 = wid * 32 + (lane >> 2);
    const int sl = ((lane & 3) ^ ((r0 >> 1) & 3)) * 8;
    const unsigned short* aP0 = A  + (size_t)(bm + r0)      * K + sl;
    const unsigned short* aP1 = A  + (size_t)(bm + r0 + 16) * K + sl;
    const unsigned short* bP0 = Bt + (size_t)(bn + r0)      * K + sl;
    const unsigned short* bP1 = Bt + (size_t)(bn + r0 + 16) * K + sl;
    unsigned short* wA0 = sA0 + wid * 1024;
    unsigned short* wB0 = sB0 + wid * 1024;
    unsigned short* wA1 = sA1 + wid * 1024;
    unsigned short* wB1 = sB1 + wid * 1024;

    const int fr  = lane & 15;
    const int h   = lane >> 4;
    const int rsl = (h ^ ((fr >> 1) & 3)) * 8;
    const int nt  = K >> 5;

    STAGE(0, wA0, wB0);
    __syncthreads();
    for (int t = 0; t < nt; t += 2) {
        STAGE((t + 1) * 32, wA1, wB1);
        COMPUTE(sA0, sB0);
        __syncthreads();
        if (t + 2 < nt) STAGE((t + 2) * 32, wA0, wB0);
        COMPUTE(sA1, sB1);
        __syncthreads();
    }

    float* wp = (float*)(smem + wid * 4608);
#pragma unroll
    for (int m = 0; m < 4; m++) {
#pragma unroll
        for (int n = 0; n < 4; n++)
#pragma unroll
            for (int r = 0; r < 4; r++)
                wp[(h * 4 + r) * 68 + n * 16 + fr] = acc[m][n][r];
#pragma unroll
        for (int rnd = 0; rnd < 4; rnd++) {
            int lr = rnd * 4 + (lane >> 4);
            int lc = (lane & 15) * 4;
            float4 v = *(float4*)&wp[lr * 68 + lc];
            int grow = bm + wm + m * 16 + lr;
            int gcol = bn + wn + lc;
            *(float4*)&outp[(size_t)grow * N + gcol] = v;
        }
    }
}

// ---------------------------------------------------------------- scan pass 1: chunk summaries
__global__ void scan_pass1(const unsigned short* __restrict__ proj, const unsigned short* __restrict__ swb,
                           float* __restrict__ rsP, float* __restrict__ rsY,
                           float4* __restrict__ ssM, float2* __restrict__ ssY) {
    const int c = blockIdx.x, b = blockIdx.y, z = blockIdx.z, tid = threadIdx.x;
    const int row0 = b * T_ + c * LC_;
    const unsigned short* base = proj + (size_t)row0 * N1_;
    if (z < 2) {
        const int s = z * 256 + tid;
        float P = 1.f, y = 0.f;
#pragma unroll 4
        for (int t = 0; t < LC_; t++) {
            const unsigned short* r = base + (size_t)t * N1_;
            float rf = b2f(r[s]);
            float rg = b2f(r[512 + s]);
            float rc = b2f(r[1024 + s]);
            y = rf * y + rg * rc;
            P *= rf;
        }
        int idx = (b * NCH_ + c) * S_ + s;
        rsP[idx] = P; rsY[idx] = y;
    } else {
        const int p = tid;
        const unsigned short* swr = swb + (size_t)row0 * HALF_;
        float m00 = 1.f, m01 = 0.f, m10 = 0.f, m11 = 1.f, y0 = 0.f, y1 = 0.f;
#pragma unroll 2
        for (int t = 0; t < LC_; t++) {
            const unsigned short* r = base + (size_t)t * N1_;
            float cw  = b2f(r[4096 + p]);
            float sw  = b2f(swr[(size_t)t * HALF_ + p]);
            float de  = b2f(r[3072 + p]);
            float dob = b2f(r[3328 + p]);
            float ge  = b2f(r[2560 + p]);
            float go  = b2f(r[2816 + p]);
            float ce  = b2f(r[2048 + p]);
            float co  = b2f(r[2304 + p]);
            float a = de * cw, bb = -de * sw, cc = dob * sw, dd = dob * cw;
            float ny0 = a * y0 + bb * y1 + ge * ce;
            float ny1 = cc * y0 + dd * y1 + go * co;
            y0 = ny0; y1 = ny1;
            float n00 = a * m00 + bb * m10, n01 = a * m01 + bb * m11;
            float n10 = cc * m00 + dd * m10, n11 = cc * m01 + dd * m11;
            m00 = n00; m01 = n01; m10 = n10; m11 = n11;
        }
        int idx = (b * NCH_ + c) * HALF_ + p;
        ssM[idx] = (float4){m00, m01, m10, m11};
        ssY[idx] = (float2){y0, y1};
    }
}

// ---------------------------------------------------------------- scan pass 2: chunk-start states
__global__ void scan_pass2(const float* __restrict__ rsP, const float* __restrict__ rsY,
                           const float4* __restrict__ ssM, const float2* __restrict__ ssY,
                           const float* __restrict__ read_init, const float* __restrict__ stable_init,
                           float* __restrict__ rsStart, float2* __restrict__ ssStart) {
    int id = blockIdx.x * 256 + threadIdx.x;
    if (id < B_ * S_) {
        int b = id / S_, s = id % S_;
        float st = read_init[s];
        for (int c = 0; c < NCH_; c++) {
            int idx = (b * NCH_ + c) * S_ + s;
            rsStart[idx] = st;
            st = rsP[idx] * st + rsY[idx];
        }
    } else {
        id -= B_ * S_;
        int b = id / HALF_, p = id % HALF_;
        float y0 = stable_init[p], y1 = stable_init[p + HALF_];
        for (int c = 0; c < NCH_; c++) {
            int idx = (b * NCH_ + c) * HALF_ + p;
            ssStart[idx] = (float2){y0, y1};
            float4 m = ssM[idx]; float2 u = ssY[idx];
            float ny0 = m.x * y0 + m.y * y1 + u.x;
            float ny1 = m.z * y0 + m.w * y1 + u.y;
            y0 = ny0; y1 = ny1;
        }
    }
}

// ---------------------------------------------------------------- scan pass 3: recompute + emit G
__global__ void scan_pass3(const unsigned short* __restrict__ proj, const unsigned short* __restrict__ swb,
                           const float* __restrict__ rsStart, const float2* __restrict__ ssStart,
                           const float4* __restrict__ mw, unsigned short* __restrict__ G) {
    const int c = blockIdx.x, b = blockIdx.y, z = blockIdx.z, tid = threadIdx.x;
    const int row0 = b * T_ + c * LC_;
    const unsigned short* base = proj + (size_t)row0 * N1_;
    if (z < 2) {
        const int s = z * 256 + tid;
        float rs = rsStart[(b * NCH_ + c) * S_ + s];
#pragma unroll 4
        for (int t = 0; t < LC_; t++) {
            const size_t row = row0 + t;
            const unsigned short* r = base + (size_t)t * N1_;
            float rf = b2f(r[s]);
            float rg = b2f(r[512 + s]);
            float rc = b2f(r[1024 + s]);
            rs = rf * rs + rg * rc;
            float q  = b2f(r[1536 + s]);
            float zz = q * rs;
            G[row * 2048 + s] = f2b(mw[row].x * silu_(zz));
        }
    } else {
        const int p = tid;
        const unsigned short* swr = swb + (size_t)row0 * HALF_;
        float2 st = ssStart[(b * NCH_ + c) * HALF_ + p];
        float y0 = st.x, y1 = st.y;
#pragma unroll 2
        for (int t = 0; t < LC_; t++) {
            const size_t row = row0 + t;
            const unsigned short* r = base + (size_t)t * N1_;
            float cw  = b2f(r[4096 + p]);
            float sw  = b2f(swr[(size_t)t * HALF_ + p]);
            float de  = b2f(r[3072 + p]);
            float dob = b2f(r[3328 + p]);
            float ge  = b2f(r[2560 + p]);
            float go  = b2f(r[2816 + p]);
            float ce  = b2f(r[2048 + p]);
            float co  = b2f(r[2304 + p]);
            float a = de * cw, bb = -de * sw, cc = dob * sw, dd = dob * cw;
            float ny0 = a * y0 + bb * y1 + ge * ce;
            float ny1 = cc * y0 + dd * y1 + go * co;
            y0 = ny0; y1 = ny1;
            float qe = b2f(r[3584 + p]);
            float qo = b2f(r[3840 + p]);
            float w1v = mw[row].y;
            G[row * 2048 + 512 + p] = f2b(w1v * silu_(qe * y0));
            G[row * 2048 + 768 + p] = f2b(w1v * silu_(qo * y1));
        }
    }
}

// ---------------------------------------------------------------- local branch elementwise
__global__ void local_ew(const unsigned short* __restrict__ proj, const float4* __restrict__ mw,
                         unsigned short* __restrict__ G) {
    int i   = blockIdx.x * 256 + threadIdx.x;
    int row = i >> 7;
    int j   = (i & 127) * 8;
    bf16x8 up = *(const bf16x8*)(proj + (size_t)row * N1_ + 4352 + j);
    bf16x8 gs = *(const bf16x8*)(proj + (size_t)row * N1_ + 5376 + j);
    float m2 = mw[row].z;
    bf16x8 o;
#pragma unroll
    for (int e = 0; e < 8; e++)
        o[e] = (short)f2b(m2 * b2f((unsigned short)up[e]) * b2f((unsigned short)gs[e]));
    *(bf16x8*)(G + (size_t)row * 2048 + 1024 + j) = o;
}

// ================================================================ host
extern "C" void kernel_launch(void* const* d_in, const int* in_sizes, int n_in,
                              void* d_out, int out_size, void* d_ws, size_t ws_size,
                              hipStream_t stream) {
    const float* x       = (const float*)d_in[0];
    const float* W_rf    = (const float*)d_in[1];
    const float* W_ri    = (const float*)d_in[2];
    const float* W_rv    = (const float*)d_in[3];
    const float* W_rq    = (const float*)d_in[4];
    const float* W_ro    = (const float*)d_in[5];
    const float* W_sw    = (const float*)d_in[6];
    const float* W_sg    = (const float*)d_in[7];
    const float* W_som   = (const float*)d_in[8];
    const float* W_sd    = (const float*)d_in[9];
    const float* W_sq    = (const float*)d_in[10];
    const float* W_so    = (const float*)d_in[11];
    const float* W_up    = (const float*)d_in[12];
    const float* W_gate  = (const float*)d_in[13];
    const float* W_down  = (const float*)d_in[14];
    const float* W_mix   = (const float*)d_in[15];
    const float* read_init   = (const float*)d_in[16];
    const float* stable_init = (const float*)d_in[17];

    char* ws = (char*)d_ws;
    size_t off = 0;
    auto alloc = [&](size_t bytes) -> void* {
        void* p = ws + off;
        off = (off + bytes + 255) & ~(size_t)255;
        return p;
    };
    unsigned short* xb   = (unsigned short*)alloc((size_t)BT_ * H_ * 2);
    unsigned short* w1   = (unsigned short*)alloc((size_t)N1_ * K1_ * 2);
    unsigned short* w2   = (unsigned short*)alloc((size_t)N2_ * K2_ * 2);
    unsigned short* proj = (unsigned short*)alloc((size_t)BT_ * N1_ * 2);
    unsigned short* swb  = (unsigned short*)alloc((size_t)BT_ * HALF_ * 2);
    float4*         mw   = (float4*)alloc((size_t)BT_ * 16);
    unsigned short* G    = (unsigned short*)alloc((size_t)BT_ * 2048 * 2);
    float*  rsP     = (float*) alloc((size_t)B_ * NCH_ * S_ * 4);
    float*  rsY     = (float*) alloc((size_t)B_ * NCH_ * S_ * 4);
    float4* ssM     = (float4*)alloc((size_t)B_ * NCH_ * HALF_ * 16);
    float2* ssY     = (float2*)alloc((size_t)B_ * NCH_ * HALF_ * 8);
    float*  rsStart = (float*) alloc((size_t)B_ * NCH_ * S_ * 4);
    float2* ssStart = (float2*)alloc((size_t)B_ * NCH_ * HALF_ * 8);
    if (off > ws_size) return;

    pack_x_kernel<<<(BT_ * H_ / 4) / 256, 256, 0, stream>>>(x, xb);

    TOps ops;
    int i = 0;
    auto add = [&](const float* s, int Kw, int Nw, int n_ofs, int k_ofs, int which) {
        ops.v[i].src = s; ops.v[i].Kw = Kw; ops.v[i].Nw = Nw;
        ops.v[i].n_ofs = n_ofs; ops.v[i].k_ofs = k_ofs; ops.v[i].which = which; i++;
    };
    add(W_rf,  1024,  512,    0,    0, 0);
    add(W_ri,  1024,  512,  512,    0, 0);
    add(W_rv,  1024,  512, 1024,    0, 0);
    add(W_rq,  1024,  512, 1536,    0, 0);
    add(W_sw,  1024,  512, 2048,    0, 0);
    add(W_sg,  1024,  512, 2560,    0, 0);
    add(W_sd,  1024,  512, 3072,    0, 0);
    add(W_sq,  1024,  512, 3584,    0, 0);
    add(W_som, 1024,  256, 4096,    0, 0);
    add(W_up,  1024, 1024, 4352,    0, 0);
    add(W_gate,1024, 1024, 5376,    0, 0);
    add(W_ro,   512, 1024,    0,    0, 1);
    add(W_so,   512, 1024,    0,  512, 1);
    add(W_down,1024, 1024,    0, 1024, 1);
    pack_w_kernel<<<dim3(32, 32, 14), 256, 0, stream>>>(ops, w1, w2);

    mix_kernel<<<BT_ / 4, 256, 0, stream>>>(x, W_mix, mw);

    gemm256_proj<<<dim3(N1_ / 256, BT_ / 256), 512, 0, stream>>>(xb, w1, proj, swb, BT_, N1_, K1_);

    scan_pass1<<<dim3(NCH_, B_, 3), 256, 0, stream>>>(proj, swb, rsP, rsY, ssM, ssY);
    scan_pass2<<<12, 256, 0, stream>>>(rsP, rsY, ssM, ssY, read_init, stable_init, rsStart, ssStart);
    scan_pass3<<<dim3(NCH_, B_, 3), 256, 0, stream>>>(proj, swb, rsStart, ssStart, mw, G);

    local_ew<<<(BT_ * LOC_ / 8) / 256, 256, 0, stream>>>(proj, mw, G);

    gemm_f32out<<<dim3(N2_ / 128, BT_ / 128), 256, 0, stream>>>(G, w2, (float*)d_out, BT_, N2_, K2_);
}

// Round 10
// 273.686 us; speedup vs baseline: 1.1857x; 1.1198x over previous
//
#include <hip/hip_runtime.h>

#define B_    4
#define T_    2048
#define H_    1024
#define S_    512
#define HALF_ 256
#define LOC_  1024
#define BT_   8192          // B*T rows
#define N1_   6400          // proj cols: 8*512 + 256 + 1024 + 1024
#define K1_   1024
#define N2_   1024
#define K2_   2048
#define NCH_  32            // scan chunks
#define LC_   64            // chunk length (T_/NCH_)

typedef __attribute__((ext_vector_type(8))) short  bf16x8;
typedef __attribute__((ext_vector_type(4))) float  f32x4;
typedef __attribute__((ext_vector_type(4))) unsigned short u16x4;

__device__ __forceinline__ float b2f(unsigned short u) {
    union { unsigned i; float f; } v; v.i = ((unsigned)u) << 16; return v.f;
}
__device__ __forceinline__ unsigned short f2b(float f) {
    union { float f; unsigned i; } v; v.f = f;
    unsigned r = v.i + 0x7fffu + ((v.i >> 16) & 1u);
    return (unsigned short)(r >> 16);
}
__device__ __forceinline__ float rcp_(float x) { return __builtin_amdgcn_rcpf(x); }
__device__ __forceinline__ float sigm_(float v) { return rcp_(1.f + __expf(-v)); }
__device__ __forceinline__ float silu_(float v) { return v * rcp_(1.f + __expf(-v)); }
__device__ __forceinline__ float tanh_(float v) { return 1.f - 2.f * rcp_(1.f + __expf(2.f * v)); }

__device__ __forceinline__ void gload16(const void* g, void* l) {
    __builtin_amdgcn_global_load_lds(
        (const __attribute__((address_space(1))) void*)g,
        (__attribute__((address_space(3))) void*)l,
        16, 0, 0);
}

// ---------------------------------------------------------------- fused pack_x + mix
// One wave per row: pack x->bf16 (vectorized) and compute softmax(x @ W_mix) on the fly.
__global__ void prep_x(const float* __restrict__ x, const float* __restrict__ Wm,
                       unsigned short* __restrict__ xb, float4* __restrict__ mw) {
    const int row  = blockIdx.x * 4 + (threadIdx.x >> 6);
    const int lane = threadIdx.x & 63;
    const float4* xr = (const float4*)(x + (size_t)row * H_);
    u16x4* xbr = (u16x4*)(xb + (size_t)row * H_);
    float s0 = 0.f, s1 = 0.f, s2 = 0.f;
#pragma unroll
    for (int p = 0; p < 4; p++) {
        const int k4 = p * 64 + lane;          // float4 index in row
        float4 v = xr[k4];
        u16x4 u;
        u.x = f2b(v.x); u.y = f2b(v.y); u.z = f2b(v.z); u.w = f2b(v.w);
        xbr[k4] = u;
        const int k3 = k4 * 12;                // (k4*4)*3
        s0 += v.x * Wm[k3 + 0] + v.y * Wm[k3 + 3] + v.z * Wm[k3 + 6] + v.w * Wm[k3 + 9];
        s1 += v.x * Wm[k3 + 1] + v.y * Wm[k3 + 4] + v.z * Wm[k3 + 7] + v.w * Wm[k3 + 10];
        s2 += v.x * Wm[k3 + 2] + v.y * Wm[k3 + 5] + v.z * Wm[k3 + 8] + v.w * Wm[k3 + 11];
    }
#pragma unroll
    for (int off = 32; off; off >>= 1) {
        s0 += __shfl_down(s0, off);
        s1 += __shfl_down(s1, off);
        s2 += __shfl_down(s2, off);
    }
    if (lane == 0) {
        float m = fmaxf(s0, fmaxf(s1, s2));
        float e0 = __expf(s0 - m), e1 = __expf(s1 - m), e2 = __expf(s2 - m);
        float inv = 1.f / (e0 + e1 + e2);
        mw[row] = (float4){ e0 * inv, e1 * inv, e2 * inv, 0.f };
    }
}

// ------------------------------------------------- transpose-pack weights to [n][k] bf16
struct TOp { const float* src; int Kw; int Nw; int n_ofs; int k_ofs; int which; };
struct TOps { TOp v[14]; };

__global__ void pack_w_kernel(TOps ops, unsigned short* __restrict__ w1, unsigned short* __restrict__ w2) {
    TOp op = ops.v[blockIdx.z];
    int kt = blockIdx.x * 32, nt = blockIdx.y * 32;
    if (kt >= op.Kw || nt >= op.Nw) return;
    __shared__ float tile[32][33];
    int tx = threadIdx.x & 31, ty = threadIdx.x >> 5;   // 32 x 8
#pragma unroll
    for (int r = 0; r < 4; r++) {
        int k = kt + ty + r * 8;
        tile[ty + r * 8][tx] = op.src[(size_t)k * op.Nw + nt + tx];
    }
    __syncthreads();
    unsigned short* dst = op.which ? w2 : w1;
    int stride = op.which ? K2_ : K1_;
#pragma unroll
    for (int r = 0; r < 4; r++) {
        int n = nt + ty + r * 8;
        dst[(size_t)(op.n_ofs + n) * stride + op.k_ofs + kt + tx] = f2b(tile[tx][ty + r * 8]);
    }
}

// ---------------------------------------------------------------- bf16 GEMM (R6-proven)
// Static double-buffered K-loop, prefetch-before-compute, one __syncthreads per K-step,
// XCD-aware bijective swizzle, wave-private vectorized LDS epilogue.
#define STAGE(kt_, dA, dB) {          \
    gload16(aP0 + (kt_), (dA));       \
    gload16(aP1 + (kt_), (dA) + 512); \
    gload16(bP0 + (kt_), (dB));       \
    gload16(bP1 + (kt_), (dB) + 512); }

#define COMPUTE(sAr, sBr) {                                                            \
    bf16x8 af[4], bfv[4];                                                              \
    _Pragma("unroll")                                                                  \
    for (int m_ = 0; m_ < 4; m_++)                                                     \
        af[m_] = *(const bf16x8*)((sAr) + (wm + m_ * 16 + fr) * 32 + rsl);             \
    _Pragma("unroll")                                                                  \
    for (int n_ = 0; n_ < 4; n_++)                                                     \
        bfv[n_] = *(const bf16x8*)((sBr) + (wn + n_ * 16 + fr) * 32 + rsl);            \
    _Pragma("unroll")                                                                  \
    for (int m_ = 0; m_ < 4; m_++)                                                     \
        _Pragma("unroll")                                                              \
        for (int n_ = 0; n_ < 4; n_++)                                                 \
            acc[m_][n_] = __builtin_amdgcn_mfma_f32_16x16x32_bf16(af[m_], bfv[n_], acc[m_][n_], 0, 0, 0); }

template<int MODE>
__global__ __launch_bounds__(256, 3) void gemm_bf16(
    const unsigned short* __restrict__ A,
    const unsigned short* __restrict__ Bt,
    void* __restrict__ Cout,
    unsigned short* __restrict__ swb,
    const int M, const int N, const int K)
{
    __shared__ __align__(16) char smem[32768];   // 2 x (8KB A + 8KB B)
    unsigned short* sA0 = (unsigned short*)smem;
    unsigned short* sB0 = (unsigned short*)(smem + 8192);
    unsigned short* sA1 = (unsigned short*)(smem + 16384);
    unsigned short* sB1 = (unsigned short*)(smem + 24576);
    const int tid  = threadIdx.x;
    const int wid  = tid >> 6;
    const int lane = tid & 63;

    // XCD swizzle: grid total % 8 == 0 -> bijective. Each XCD owns 8 bm-rows x all bn.
    const int flat = blockIdx.y * gridDim.x + blockIdx.x;
    const int xcd  = flat & 7;
    const int ii   = flat >> 3;
    const int bm   = ((xcd << 3) + (ii & 7)) * 128;
    const int bn   = (ii >> 3) * 128;

    const int wm = (wid >> 1) * 64;
    const int wn = (wid & 1) * 64;

    f32x4 acc[4][4];
#pragma unroll
    for (int m = 0; m < 4; m++)
#pragma unroll
        for (int n = 0; n < 4; n++) acc[m][n] = (f32x4){0.f, 0.f, 0.f, 0.f};

    const int r0 = wid * 32 + (lane >> 2);
    const int sl = ((lane & 3) ^ ((r0 >> 1) & 3)) * 8;
    const unsigned short* aP0 = A  + (size_t)(bm + r0)      * K + sl;
    const unsigned short* aP1 = A  + (size_t)(bm + r0 + 16) * K + sl;
    const unsigned short* bP0 = Bt + (size_t)(bn + r0)      * K + sl;
    const unsigned short* bP1 = Bt + (size_t)(bn + r0 + 16) * K + sl;
    unsigned short* wA0 = sA0 + wid * 1024;
    unsigned short* wB0 = sB0 + wid * 1024;
    unsigned short* wA1 = sA1 + wid * 1024;
    unsigned short* wB1 = sB1 + wid * 1024;

    const int fr  = lane & 15;
    const int h   = lane >> 4;
    const int rsl = (h ^ ((fr >> 1) & 3)) * 8;
    const int nt  = K >> 5;   // 32 or 64: always even

    STAGE(0, wA0, wB0);
    __syncthreads();
    for (int t = 0; t < nt; t += 2) {
        STAGE((t + 1) * 32, wA1, wB1);   // prefetch flies during compute of buf0
        COMPUTE(sA0, sB0);
        __syncthreads();                 // drains prefetch + protects buf0 rewrite
        if (t + 2 < nt) STAGE((t + 2) * 32, wA0, wB0);
        COMPUTE(sA1, sB1);
        __syncthreads();
    }

    if (MODE == 0) {
        // wave-private f32 patch (16 rows x pitch 68), vectorized float4 stores
        float* outp = (float*)Cout;
        float* wp = (float*)(smem + wid * 4608);
#pragma unroll
        for (int m = 0; m < 4; m++) {
#pragma unroll
            for (int n = 0; n < 4; n++)
#pragma unroll
                for (int r = 0; r < 4; r++)
                    wp[(h * 4 + r) * 68 + n * 16 + fr] = acc[m][n][r];
#pragma unroll
            for (int rnd = 0; rnd < 4; rnd++) {
                int lr = rnd * 4 + (lane >> 4);
                int lc = (lane & 15) * 4;
                float4 v = *(float4*)&wp[lr * 68 + lc];
                int grow = bm + wm + m * 16 + lr;
                int gcol = bn + wn + lc;
                *(float4*)&outp[(size_t)grow * N + gcol] = v;
            }
        }
    } else {
        // region uniform per 128-col block: 0=tanh 1=sigm 2=silu 3=id 4=sigm(-v) 5=som
        int reg;
        if      (bn < 512)  reg = 0;
        else if (bn < 1024) reg = 1;
        else if (bn < 1536) reg = 2;
        else if (bn < 2048) reg = 3;
        else if (bn < 2560) reg = 2;
        else if (bn < 3072) reg = 1;
        else if (bn < 3584) reg = 4;
        else if (bn < 4096) reg = 3;
        else if (bn < 4352) reg = 5;
        else if (bn < 5376) reg = 3;
        else                reg = 2;

        unsigned short* proj = (unsigned short*)Cout;
        unsigned short* wp = (unsigned short*)(smem + wid * 2304);  // 16 x pitch72 bf16
        const int nsub = (reg == 5) ? 2 : 1;
#pragma unroll
        for (int m = 0; m < 4; m++) {
            for (int sub = 0; sub < nsub; sub++) {
#pragma unroll
                for (int n = 0; n < 4; n++)
#pragma unroll
                    for (int r = 0; r < 4; r++) {
                        float v = acc[m][n][r];
                        float o;
                        if      (reg == 0) o = tanh_(v);
                        else if (reg == 1) o = sigm_(v);
                        else if (reg == 2) o = silu_(v);
                        else if (reg == 3) o = v;
                        else if (reg == 4) o = sigm_(-v);
                        else {
                            float om = 3.14159265358979f * tanh_(v);
                            o = sub ? __sinf(om) : __cosf(om);
                        }
                        wp[(h * 4 + r) * 72 + n * 16 + fr] = f2b(o);
                    }
#pragma unroll
                for (int p = 0; p < 2; p++) {
                    int lr = p * 8 + (lane >> 3);
                    int lc = (lane & 7) * 8;
                    bf16x8 v = *(bf16x8*)(wp + lr * 72 + lc);
                    int grow = bm + wm + m * 16 + lr;
                    int gcol = bn + wn + lc;
                    if (sub == 0)
                        *(bf16x8*)(proj + (size_t)grow * N + gcol) = v;
                    else
                        *(bf16x8*)(swb + (size_t)grow * HALF_ + (gcol - 4096)) = v;
                }
            }
        }
    }
}

// ---------------------------------------------------------------- scan pass 1: chunk summaries
__global__ void scan_pass1(const unsigned short* __restrict__ proj, const unsigned short* __restrict__ swb,
                           float* __restrict__ rsP, float* __restrict__ rsY,
                           float4* __restrict__ ssM, float2* __restrict__ ssY) {
    const int c = blockIdx.x, b = blockIdx.y, z = blockIdx.z, tid = threadIdx.x;
    const int row0 = b * T_ + c * LC_;
    const unsigned short* base = proj + (size_t)row0 * N1_;
    if (z < 2) {
        const int s = z * 256 + tid;
        float P = 1.f, y = 0.f;
#pragma unroll 4
        for (int t = 0; t < LC_; t++) {
            const unsigned short* r = base + (size_t)t * N1_;
            float rf = b2f(r[s]);
            float rg = b2f(r[512 + s]);
            float rc = b2f(r[1024 + s]);
            y = rf * y + rg * rc;
            P *= rf;
        }
        int idx = (b * NCH_ + c) * S_ + s;
        rsP[idx] = P; rsY[idx] = y;
    } else {
        const int p = tid;
        const unsigned short* swr = swb + (size_t)row0 * HALF_;
        float m00 = 1.f, m01 = 0.f, m10 = 0.f, m11 = 1.f, y0 = 0.f, y1 = 0.f;
#pragma unroll 2
        for (int t = 0; t < LC_; t++) {
            const unsigned short* r = base + (size_t)t * N1_;
            float cw  = b2f(r[4096 + p]);
            float sw  = b2f(swr[(size_t)t * HALF_ + p]);
            float de  = b2f(r[3072 + p]);
            float dob = b2f(r[3328 + p]);
            float ge  = b2f(r[2560 + p]);
            float go  = b2f(r[2816 + p]);
            float ce  = b2f(r[2048 + p]);
            float co  = b2f(r[2304 + p]);
            float a = de * cw, bb = -de * sw, cc = dob * sw, dd = dob * cw;
            float ny0 = a * y0 + bb * y1 + ge * ce;
            float ny1 = cc * y0 + dd * y1 + go * co;
            y0 = ny0; y1 = ny1;
            float n00 = a * m00 + bb * m10, n01 = a * m01 + bb * m11;
            float n10 = cc * m00 + dd * m10, n11 = cc * m01 + dd * m11;
            m00 = n00; m01 = n01; m10 = n10; m11 = n11;
        }
        int idx = (b * NCH_ + c) * HALF_ + p;
        ssM[idx] = (float4){m00, m01, m10, m11};
        ssY[idx] = (float2){y0, y1};
    }
}

// ---------------------------------------------------------------- scan pass 2: chunk-start states
__global__ void scan_pass2(const float* __restrict__ rsP, const float* __restrict__ rsY,
                           const float4* __restrict__ ssM, const float2* __restrict__ ssY,
                           const float* __restrict__ read_init, const float* __restrict__ stable_init,
                           float* __restrict__ rsStart, float2* __restrict__ ssStart) {
    int id = blockIdx.x * 256 + threadIdx.x;
    if (id < B_ * S_) {
        int b = id / S_, s = id % S_;
        float st = read_init[s];
        for (int c = 0; c < NCH_; c++) {
            int idx = (b * NCH_ + c) * S_ + s;
            rsStart[idx] = st;
            st = rsP[idx] * st + rsY[idx];
        }
    } else {
        id -= B_ * S_;
        int b = id / HALF_, p = id % HALF_;
        float y0 = stable_init[p], y1 = stable_init[p + HALF_];
        for (int c = 0; c < NCH_; c++) {
            int idx = (b * NCH_ + c) * HALF_ + p;
            ssStart[idx] = (float2){y0, y1};
            float4 m = ssM[idx]; float2 u = ssY[idx];
            float ny0 = m.x * y0 + m.y * y1 + u.x;
            float ny1 = m.z * y0 + m.w * y1 + u.y;
            y0 = ny0; y1 = ny1;
        }
    }
}

// ---------------------------------------------------------------- scan pass 3: recompute + emit G
__global__ void scan_pass3(const unsigned short* __restrict__ proj, const unsigned short* __restrict__ swb,
                           const float* __restrict__ rsStart, const float2* __restrict__ ssStart,
                           const float4* __restrict__ mw, unsigned short* __restrict__ G) {
    const int c = blockIdx.x, b = blockIdx.y, z = blockIdx.z, tid = threadIdx.x;
    const int row0 = b * T_ + c * LC_;
    const unsigned short* base = proj + (size_t)row0 * N1_;
    if (z < 2) {
        const int s = z * 256 + tid;
        float rs = rsStart[(b * NCH_ + c) * S_ + s];
#pragma unroll 4
        for (int t = 0; t < LC_; t++) {
            const size_t row = row0 + t;
            const unsigned short* r = base + (size_t)t * N1_;
            float rf = b2f(r[s]);
            float rg = b2f(r[512 + s]);
            float rc = b2f(r[1024 + s]);
            rs = rf * rs + rg * rc;
            float q  = b2f(r[1536 + s]);
            float zz = q * rs;
            G[row * 2048 + s] = f2b(mw[row].x * silu_(zz));
        }
    } else {
        const int p = tid;
        const unsigned short* swr = swb + (size_t)row0 * HALF_;
        float2 st = ssStart[(b * NCH_ + c) * HALF_ + p];
        float y0 = st.x, y1 = st.y;
#pragma unroll 2
        for (int t = 0; t < LC_; t++) {
            const size_t row = row0 + t;
            const unsigned short* r = base + (size_t)t * N1_;
            float cw  = b2f(r[4096 + p]);
            float sw  = b2f(swr[(size_t)t * HALF_ + p]);
            float de  = b2f(r[3072 + p]);
            float dob = b2f(r[3328 + p]);
            float ge  = b2f(r[2560 + p]);
            float go  = b2f(r[2816 + p]);
            float ce  = b2f(r[2048 + p]);
            float co  = b2f(r[2304 + p]);
            float a = de * cw, bb = -de * sw, cc = dob * sw, dd = dob * cw;
            float ny0 = a * y0 + bb * y1 + ge * ce;
            float ny1 = cc * y0 + dd * y1 + go * co;
            y0 = ny0; y1 = ny1;
            float qe = b2f(r[3584 + p]);
            float qo = b2f(r[3840 + p]);
            float w1v = mw[row].y;
            G[row * 2048 + 512 + p] = f2b(w1v * silu_(qe * y0));
            G[row * 2048 + 768 + p] = f2b(w1v * silu_(qo * y1));
        }
    }
}

// ---------------------------------------------------------------- local branch elementwise
__global__ void local_ew(const unsigned short* __restrict__ proj, const float4* __restrict__ mw,
                         unsigned short* __restrict__ G) {
    int i   = blockIdx.x * 256 + threadIdx.x;
    int row = i >> 7;
    int j   = (i & 127) * 8;
    bf16x8 up = *(const bf16x8*)(proj + (size_t)row * N1_ + 4352 + j);
    bf16x8 gs = *(const bf16x8*)(proj + (size_t)row * N1_ + 5376 + j);
    float m2 = mw[row].z;
    bf16x8 o;
#pragma unroll
    for (int e = 0; e < 8; e++)
        o[e] = (short)f2b(m2 * b2f((unsigned short)up[e]) * b2f((unsigned short)gs[e]));
    *(bf16x8*)(G + (size_t)row * 2048 + 1024 + j) = o;
}

// ================================================================ host
extern "C" void kernel_launch(void* const* d_in, const int* in_sizes, int n_in,
                              void* d_out, int out_size, void* d_ws, size_t ws_size,
                              hipStream_t stream) {
    const float* x       = (const float*)d_in[0];
    const float* W_rf    = (const float*)d_in[1];
    const float* W_ri    = (const float*)d_in[2];
    const float* W_rv    = (const float*)d_in[3];
    const float* W_rq    = (const float*)d_in[4];
    const float* W_ro    = (const float*)d_in[5];
    const float* W_sw    = (const float*)d_in[6];
    const float* W_sg    = (const float*)d_in[7];
    const float* W_som   = (const float*)d_in[8];
    const float* W_sd    = (const float*)d_in[9];
    const float* W_sq    = (const float*)d_in[10];
    const float* W_so    = (const float*)d_in[11];
    const float* W_up    = (const float*)d_in[12];
    const float* W_gate  = (const float*)d_in[13];
    const float* W_down  = (const float*)d_in[14];
    const float* W_mix   = (const float*)d_in[15];
    const float* read_init   = (const float*)d_in[16];
    const float* stable_init = (const float*)d_in[17];

    char* ws = (char*)d_ws;
    size_t off = 0;
    auto alloc = [&](size_t bytes) -> void* {
        void* p = ws + off;
        off = (off + bytes + 255) & ~(size_t)255;
        return p;
    };
    unsigned short* xb   = (unsigned short*)alloc((size_t)BT_ * H_ * 2);
    unsigned short* w1   = (unsigned short*)alloc((size_t)N1_ * K1_ * 2);
    unsigned short* w2   = (unsigned short*)alloc((size_t)N2_ * K2_ * 2);
    unsigned short* proj = (unsigned short*)alloc((size_t)BT_ * N1_ * 2);
    unsigned short* swb  = (unsigned short*)alloc((size_t)BT_ * HALF_ * 2);
    float4*         mw   = (float4*)alloc((size_t)BT_ * 16);
    unsigned short* G    = (unsigned short*)alloc((size_t)BT_ * 2048 * 2);
    float*  rsP     = (float*) alloc((size_t)B_ * NCH_ * S_ * 4);
    float*  rsY     = (float*) alloc((size_t)B_ * NCH_ * S_ * 4);
    float4* ssM     = (float4*)alloc((size_t)B_ * NCH_ * HALF_ * 16);
    float2* ssY     = (float2*)alloc((size_t)B_ * NCH_ * HALF_ * 8);
    float*  rsStart = (float*) alloc((size_t)B_ * NCH_ * S_ * 4);
    float2* ssStart = (float2*)alloc((size_t)B_ * NCH_ * HALF_ * 8);
    if (off > ws_size) return;

    prep_x<<<BT_ / 4, 256, 0, stream>>>(x, W_mix, xb, mw);

    TOps ops;
    int i = 0;
    auto add = [&](const float* s, int Kw, int Nw, int n_ofs, int k_ofs, int which) {
        ops.v[i].src = s; ops.v[i].Kw = Kw; ops.v[i].Nw = Nw;
        ops.v[i].n_ofs = n_ofs; ops.v[i].k_ofs = k_ofs; ops.v[i].which = which; i++;
    };
    add(W_rf,  1024,  512,    0,    0, 0);
    add(W_ri,  1024,  512,  512,    0, 0);
    add(W_rv,  1024,  512, 1024,    0, 0);
    add(W_rq,  1024,  512, 1536,    0, 0);
    add(W_sw,  1024,  512, 2048,    0, 0);
    add(W_sg,  1024,  512, 2560,    0, 0);
    add(W_sd,  1024,  512, 3072,    0, 0);
    add(W_sq,  1024,  512, 3584,    0, 0);
    add(W_som, 1024,  256, 4096,    0, 0);
    add(W_up,  1024, 1024, 4352,    0, 0);
    add(W_gate,1024, 1024, 5376,    0, 0);
    add(W_ro,   512, 1024,    0,    0, 1);
    add(W_so,   512, 1024,    0,  512, 1);
    add(W_down,1024, 1024,    0, 1024, 1);
    pack_w_kernel<<<dim3(32, 32, 14), 256, 0, stream>>>(ops, w1, w2);

    gemm_bf16<1><<<dim3(N1_ / 128, BT_ / 128), 256, 0, stream>>>(xb, w1, (void*)proj, swb, BT_, N1_, K1_);

    scan_pass1<<<dim3(NCH_, B_, 3), 256, 0, stream>>>(proj, swb, rsP, rsY, ssM, ssY);
    scan_pass2<<<12, 256, 0, stream>>>(rsP, rsY, ssM, ssY, read_init, stable_init, rsStart, ssStart);
    scan_pass3<<<dim3(NCH_, B_, 3), 256, 0, stream>>>(proj, swb, rsStart, ssStart, mw, G);

    local_ew<<<(BT_ * LOC_ / 8) / 256, 256, 0, stream>>>(proj, mw, G);

    gemm_bf16<0><<<dim3(N2_ / 128, BT_ / 128), 256, 0, stream>>>(G, w2, d_out, nullptr, BT_, N2_, K2_);
}

// Round 11
// 230.480 us; speedup vs baseline: 1.4080x; 1.1875x over previous
//
#include <hip/hip_runtime.h>

#define B_    4
#define T_    2048
#define H_    1024
#define S_    512
#define HALF_ 256
#define LOC_  1024
#define BT_   8192          // B*T rows
#define N1_   6400          // proj cols: 8*512 + 256 + 1024 + 1024 (up/gate interleaved)
#define K1_   1024
#define N2_   1024
#define K2_   2048
#define NCH_  32            // scan chunks
#define LC_   64            // chunk length (T_/NCH_)

typedef __attribute__((ext_vector_type(8))) short  bf16x8;
typedef __attribute__((ext_vector_type(4))) float  f32x4;
typedef __attribute__((ext_vector_type(4))) unsigned short u16x4;

__device__ __forceinline__ float b2f(unsigned short u) {
    union { unsigned i; float f; } v; v.i = ((unsigned)u) << 16; return v.f;
}
__device__ __forceinline__ unsigned short f2b(float f) {
    union { float f; unsigned i; } v; v.f = f;
    unsigned r = v.i + 0x7fffu + ((v.i >> 16) & 1u);
    return (unsigned short)(r >> 16);
}
__device__ __forceinline__ float rcp_(float x) { return __builtin_amdgcn_rcpf(x); }
__device__ __forceinline__ float sigm_(float v) { return rcp_(1.f + __expf(-v)); }
__device__ __forceinline__ float silu_(float v) { return v * rcp_(1.f + __expf(-v)); }
__device__ __forceinline__ float tanh_(float v) { return 1.f - 2.f * rcp_(1.f + __expf(2.f * v)); }

__device__ __forceinline__ void gload16(const void* g, void* l) {
    __builtin_amdgcn_global_load_lds(
        (const __attribute__((address_space(1))) void*)g,
        (__attribute__((address_space(3))) void*)l,
        16, 0, 0);
}

// ---------------------------------------------------------------- fused pack_x + mix
__global__ void prep_x(const float* __restrict__ x, const float* __restrict__ Wm,
                       unsigned short* __restrict__ xb, float4* __restrict__ mw) {
    const int row  = blockIdx.x * 4 + (threadIdx.x >> 6);
    const int lane = threadIdx.x & 63;
    const float4* xr = (const float4*)(x + (size_t)row * H_);
    u16x4* xbr = (u16x4*)(xb + (size_t)row * H_);
    float s0 = 0.f, s1 = 0.f, s2 = 0.f;
#pragma unroll
    for (int p = 0; p < 4; p++) {
        const int k4 = p * 64 + lane;
        float4 v = xr[k4];
        u16x4 u;
        u.x = f2b(v.x); u.y = f2b(v.y); u.z = f2b(v.z); u.w = f2b(v.w);
        xbr[k4] = u;
        const int k3 = k4 * 12;
        s0 += v.x * Wm[k3 + 0] + v.y * Wm[k3 + 3] + v.z * Wm[k3 + 6] + v.w * Wm[k3 + 9];
        s1 += v.x * Wm[k3 + 1] + v.y * Wm[k3 + 4] + v.z * Wm[k3 + 7] + v.w * Wm[k3 + 10];
        s2 += v.x * Wm[k3 + 2] + v.y * Wm[k3 + 5] + v.z * Wm[k3 + 8] + v.w * Wm[k3 + 11];
    }
#pragma unroll
    for (int off = 32; off; off >>= 1) {
        s0 += __shfl_down(s0, off);
        s1 += __shfl_down(s1, off);
        s2 += __shfl_down(s2, off);
    }
    if (lane == 0) {
        float m = fmaxf(s0, fmaxf(s1, s2));
        float e0 = __expf(s0 - m), e1 = __expf(s1 - m), e2 = __expf(s2 - m);
        float inv = 1.f / (e0 + e1 + e2);
        mw[row] = (float4){ e0 * inv, e1 * inv, e2 * inv, 0.f };
    }
}

// ------------------------------------------------- transpose-pack weights to [n][k] bf16
// ilv: 0 = plain; 1 = up-half of 32-col superblock; 2 = gate-half.
struct TOp { const float* src; int Kw; int Nw; int n_ofs; int k_ofs; int which; int ilv; };
struct TOps { TOp v[14]; };

__global__ void pack_w_kernel(TOps ops, unsigned short* __restrict__ w1, unsigned short* __restrict__ w2) {
    TOp op = ops.v[blockIdx.z];
    int kt = blockIdx.x * 32, nt = blockIdx.y * 32;
    if (kt >= op.Kw || nt >= op.Nw) return;
    __shared__ float tile[32][33];
    int tx = threadIdx.x & 31, ty = threadIdx.x >> 5;   // 32 x 8
#pragma unroll
    for (int r = 0; r < 4; r++) {
        int k = kt + ty + r * 8;
        tile[ty + r * 8][tx] = op.src[(size_t)k * op.Nw + nt + tx];
    }
    __syncthreads();
    unsigned short* dst = op.which ? w2 : w1;
    int stride = op.which ? K2_ : K1_;
#pragma unroll
    for (int r = 0; r < 4; r++) {
        int n = nt + ty + r * 8;
        int dcol;
        if (op.ilv)
            dcol = op.n_ofs + ((n >> 4) << 5) + ((op.ilv == 2) ? 16 : 0) + (n & 15);
        else
            dcol = op.n_ofs + n;
        dst[(size_t)dcol * stride + op.k_ofs + kt + tx] = f2b(tile[tx][ty + r * 8]);
    }
}

// ---------------------------------------------------------------- bf16 GEMM (R6-proven)
// Static double-buffered K-loop, prefetch-before-compute, one __syncthreads per K-step,
// XCD-aware bijective swizzle, wave-private vectorized LDS epilogue.
// MODE 1 regions: 0=tanh 1=sigm 2=silu 3=id 4=sigm(-v) 5=som(cos/sin)
//                 6=fused local branch: G = mw.z * up * silu(gate)  (up/gate interleaved cols)
#define STAGE(kt_, dA, dB) {          \
    gload16(aP0 + (kt_), (dA));       \
    gload16(aP1 + (kt_), (dA) + 512); \
    gload16(bP0 + (kt_), (dB));       \
    gload16(bP1 + (kt_), (dB) + 512); }

#define COMPUTE(sAr, sBr) {                                                            \
    bf16x8 af[4], bfv[4];                                                              \
    _Pragma("unroll")                                                                  \
    for (int m_ = 0; m_ < 4; m_++)                                                     \
        af[m_] = *(const bf16x8*)((sAr) + (wm + m_ * 16 + fr) * 32 + rsl);             \
    _Pragma("unroll")                                                                  \
    for (int n_ = 0; n_ < 4; n_++)                                                     \
        bfv[n_] = *(const bf16x8*)((sBr) + (wn + n_ * 16 + fr) * 32 + rsl);            \
    _Pragma("unroll")                                                                  \
    for (int m_ = 0; m_ < 4; m_++)                                                     \
        _Pragma("unroll")                                                              \
        for (int n_ = 0; n_ < 4; n_++)                                                 \
            acc[m_][n_] = __builtin_amdgcn_mfma_f32_16x16x32_bf16(af[m_], bfv[n_], acc[m_][n_], 0, 0, 0); }

template<int MODE>
__global__ __launch_bounds__(256, 3) void gemm_bf16(
    const unsigned short* __restrict__ A,
    const unsigned short* __restrict__ Bt,
    void* __restrict__ Cout,
    unsigned short* __restrict__ swb,
    const float4* __restrict__ mwp,
    unsigned short* __restrict__ G,
    const int M, const int N, const int K)
{
    __shared__ __align__(16) char smem[32768];   // 2 x (8KB A + 8KB B)
    unsigned short* sA0 = (unsigned short*)smem;
    unsigned short* sB0 = (unsigned short*)(smem + 8192);
    unsigned short* sA1 = (unsigned short*)(smem + 16384);
    unsigned short* sB1 = (unsigned short*)(smem + 24576);
    const int tid  = threadIdx.x;
    const int wid  = tid >> 6;
    const int lane = tid & 63;

    // XCD swizzle: grid total % 8 == 0 -> bijective. Each XCD owns 8 bm-rows x all bn.
    const int flat = blockIdx.y * gridDim.x + blockIdx.x;
    const int xcd  = flat & 7;
    const int ii   = flat >> 3;
    const int bm   = ((xcd << 3) + (ii & 7)) * 128;
    const int bn   = (ii >> 3) * 128;

    const int wm = (wid >> 1) * 64;
    const int wn = (wid & 1) * 64;

    f32x4 acc[4][4];
#pragma unroll
    for (int m = 0; m < 4; m++)
#pragma unroll
        for (int n = 0; n < 4; n++) acc[m][n] = (f32x4){0.f, 0.f, 0.f, 0.f};

    const int r0 = wid * 32 + (lane >> 2);
    const int sl = ((lane & 3) ^ ((r0 >> 1) & 3)) * 8;
    const unsigned short* aP0 = A  + (size_t)(bm + r0)      * K + sl;
    const unsigned short* aP1 = A  + (size_t)(bm + r0 + 16) * K + sl;
    const unsigned short* bP0 = Bt + (size_t)(bn + r0)      * K + sl;
    const unsigned short* bP1 = Bt + (size_t)(bn + r0 + 16) * K + sl;
    unsigned short* wA0 = sA0 + wid * 1024;
    unsigned short* wB0 = sB0 + wid * 1024;
    unsigned short* wA1 = sA1 + wid * 1024;
    unsigned short* wB1 = sB1 + wid * 1024;

    const int fr  = lane & 15;
    const int h   = lane >> 4;
    const int rsl = (h ^ ((fr >> 1) & 3)) * 8;
    const int nt  = K >> 5;   // 32 or 64: always even

    STAGE(0, wA0, wB0);
    __syncthreads();
    for (int t = 0; t < nt; t += 2) {
        STAGE((t + 1) * 32, wA1, wB1);
        COMPUTE(sA0, sB0);
        __syncthreads();
        if (t + 2 < nt) STAGE((t + 2) * 32, wA0, wB0);
        COMPUTE(sA1, sB1);
        __syncthreads();
    }

    if (MODE == 0) {
        float* outp = (float*)Cout;
        float* wp = (float*)(smem + wid * 4608);
#pragma unroll
        for (int m = 0; m < 4; m++) {
#pragma unroll
            for (int n = 0; n < 4; n++)
#pragma unroll
                for (int r = 0; r < 4; r++)
                    wp[(h * 4 + r) * 68 + n * 16 + fr] = acc[m][n][r];
#pragma unroll
            for (int rnd = 0; rnd < 4; rnd++) {
                int lr = rnd * 4 + (lane >> 4);
                int lc = (lane & 15) * 4;
                float4 v = *(float4*)&wp[lr * 68 + lc];
                int grow = bm + wm + m * 16 + lr;
                int gcol = bn + wn + lc;
                *(float4*)&outp[(size_t)grow * N + gcol] = v;
            }
        }
    } else {
        int reg;
        if      (bn < 512)  reg = 0;
        else if (bn < 1024) reg = 1;
        else if (bn < 1536) reg = 2;
        else if (bn < 2048) reg = 3;
        else if (bn < 2560) reg = 2;
        else if (bn < 3072) reg = 1;
        else if (bn < 3584) reg = 4;
        else if (bn < 4096) reg = 3;
        else if (bn < 4352) reg = 5;
        else                reg = 6;   // fused up/gate -> G

        unsigned short* proj = (unsigned short*)Cout;
        if (reg == 6) {
            // n-pairs (0,1) and (2,3) hold (up, gate) for the same j; emit G directly.
            unsigned short* wp = (unsigned short*)(smem + wid * 2304);  // 16 x pitch 40
            const int sb = (bn + wn - 4352) >> 5;                       // 32-col superblock idx
#pragma unroll
            for (int m = 0; m < 4; m++) {
#pragma unroll
                for (int pr = 0; pr < 2; pr++)
#pragma unroll
                    for (int r = 0; r < 4; r++) {
                        int row = bm + wm + m * 16 + h * 4 + r;
                        float m2 = mwp[row].z;
                        float up = acc[m][pr * 2][r];
                        float gt = acc[m][pr * 2 + 1][r];
                        wp[(h * 4 + r) * 40 + pr * 16 + fr] = f2b(m2 * up * silu_(gt));
                    }
                {
                    int lr = lane >> 2;
                    int lc = (lane & 3) * 8;
                    bf16x8 v = *(bf16x8*)(wp + lr * 40 + lc);
                    int grow = bm + wm + m * 16 + lr;
                    *(bf16x8*)(G + (size_t)grow * 2048 + 1024 + sb * 16 + lc) = v;
                }
            }
        } else {
            unsigned short* wp = (unsigned short*)(smem + wid * 2304);  // 16 x pitch72 bf16
            const int nsub = (reg == 5) ? 2 : 1;
#pragma unroll
            for (int m = 0; m < 4; m++) {
                for (int sub = 0; sub < nsub; sub++) {
#pragma unroll
                    for (int n = 0; n < 4; n++)
#pragma unroll
                        for (int r = 0; r < 4; r++) {
                            float v = acc[m][n][r];
                            float o;
                            if      (reg == 0) o = tanh_(v);
                            else if (reg == 1) o = sigm_(v);
                            else if (reg == 2) o = silu_(v);
                            else if (reg == 3) o = v;
                            else if (reg == 4) o = sigm_(-v);
                            else {
                                float om = 3.14159265358979f * tanh_(v);
                                o = sub ? __sinf(om) : __cosf(om);
                            }
                            wp[(h * 4 + r) * 72 + n * 16 + fr] = f2b(o);
                        }
#pragma unroll
                    for (int p = 0; p < 2; p++) {
                        int lr = p * 8 + (lane >> 3);
                        int lc = (lane & 7) * 8;
                        bf16x8 v = *(bf16x8*)(wp + lr * 72 + lc);
                        int grow = bm + wm + m * 16 + lr;
                        int gcol = bn + wn + lc;
                        if (sub == 0)
                            *(bf16x8*)(proj + (size_t)grow * N + gcol) = v;
                        else
                            *(bf16x8*)(swb + (size_t)grow * HALF_ + (gcol - 4096)) = v;
                    }
                }
            }
        }
    }
}

// ---------------------------------------------------------------- scan pass 1: chunk summaries
__global__ void scan_pass1(const unsigned short* __restrict__ proj, const unsigned short* __restrict__ swb,
                           float* __restrict__ rsP, float* __restrict__ rsY,
                           float4* __restrict__ ssM, float2* __restrict__ ssY) {
    const int c = blockIdx.x, b = blockIdx.y, z = blockIdx.z, tid = threadIdx.x;
    const int row0 = b * T_ + c * LC_;
    const unsigned short* base = proj + (size_t)row0 * N1_;
    if (z < 2) {
        const int s = z * 256 + tid;
        float P = 1.f, y = 0.f;
#pragma unroll 4
        for (int t = 0; t < LC_; t++) {
            const unsigned short* r = base + (size_t)t * N1_;
            float rf = b2f(r[s]);
            float rg = b2f(r[512 + s]);
            float rc = b2f(r[1024 + s]);
            y = rf * y + rg * rc;
            P *= rf;
        }
        int idx = (b * NCH_ + c) * S_ + s;
        rsP[idx] = P; rsY[idx] = y;
    } else {
        const int p = tid;
        const unsigned short* swr = swb + (size_t)row0 * HALF_;
        float m00 = 1.f, m01 = 0.f, m10 = 0.f, m11 = 1.f, y0 = 0.f, y1 = 0.f;
#pragma unroll 2
        for (int t = 0; t < LC_; t++) {
            const unsigned short* r = base + (size_t)t * N1_;
            float cw  = b2f(r[4096 + p]);
            float sw  = b2f(swr[(size_t)t * HALF_ + p]);
            float de  = b2f(r[3072 + p]);
            float dob = b2f(r[3328 + p]);
            float ge  = b2f(r[2560 + p]);
            float go  = b2f(r[2816 + p]);
            float ce  = b2f(r[2048 + p]);
            float co  = b2f(r[2304 + p]);
            float a = de * cw, bb = -de * sw, cc = dob * sw, dd = dob * cw;
            float ny0 = a * y0 + bb * y1 + ge * ce;
            float ny1 = cc * y0 + dd * y1 + go * co;
            y0 = ny0; y1 = ny1;
            float n00 = a * m00 + bb * m10, n01 = a * m01 + bb * m11;
            float n10 = cc * m00 + dd * m10, n11 = cc * m01 + dd * m11;
            m00 = n00; m01 = n01; m10 = n10; m11 = n11;
        }
        int idx = (b * NCH_ + c) * HALF_ + p;
        ssM[idx] = (float4){m00, m01, m10, m11};
        ssY[idx] = (float2){y0, y1};
    }
}

// ---------------------------------------------------------------- scan pass 2: chunk-start states
__global__ void scan_pass2(const float* __restrict__ rsP, const float* __restrict__ rsY,
                           const float4* __restrict__ ssM, const float2* __restrict__ ssY,
                           const float* __restrict__ read_init, const float* __restrict__ stable_init,
                           float* __restrict__ rsStart, float2* __restrict__ ssStart) {
    int id = blockIdx.x * 256 + threadIdx.x;
    if (id < B_ * S_) {
        int b = id / S_, s = id % S_;
        float st = read_init[s];
        for (int c = 0; c < NCH_; c++) {
            int idx = (b * NCH_ + c) * S_ + s;
            rsStart[idx] = st;
            st = rsP[idx] * st + rsY[idx];
        }
    } else {
        id -= B_ * S_;
        int b = id / HALF_, p = id % HALF_;
        float y0 = stable_init[p], y1 = stable_init[p + HALF_];
        for (int c = 0; c < NCH_; c++) {
            int idx = (b * NCH_ + c) * HALF_ + p;
            ssStart[idx] = (float2){y0, y1};
            float4 m = ssM[idx]; float2 u = ssY[idx];
            float ny0 = m.x * y0 + m.y * y1 + u.x;
            float ny1 = m.z * y0 + m.w * y1 + u.y;
            y0 = ny0; y1 = ny1;
        }
    }
}

// ---------------------------------------------------------------- scan pass 3: recompute + emit G
__global__ void scan_pass3(const unsigned short* __restrict__ proj, const unsigned short* __restrict__ swb,
                           const float* __restrict__ rsStart, const float2* __restrict__ ssStart,
                           const float4* __restrict__ mw, unsigned short* __restrict__ G) {
    const int c = blockIdx.x, b = blockIdx.y, z = blockIdx.z, tid = threadIdx.x;
    const int row0 = b * T_ + c * LC_;
    const unsigned short* base = proj + (size_t)row0 * N1_;
    if (z < 2) {
        const int s = z * 256 + tid;
        float rs = rsStart[(b * NCH_ + c) * S_ + s];
#pragma unroll 4
        for (int t = 0; t < LC_; t++) {
            const size_t row = row0 + t;
            const unsigned short* r = base + (size_t)t * N1_;
            float rf = b2f(r[s]);
            float rg = b2f(r[512 + s]);
            float rc = b2f(r[1024 + s]);
            rs = rf * rs + rg * rc;
            float q  = b2f(r[1536 + s]);
            float zz = q * rs;
            G[row * 2048 + s] = f2b(mw[row].x * silu_(zz));
        }
    } else {
        const int p = tid;
        const unsigned short* swr = swb + (size_t)row0 * HALF_;
        float2 st = ssStart[(b * NCH_ + c) * HALF_ + p];
        float y0 = st.x, y1 = st.y;
#pragma unroll 2
        for (int t = 0; t < LC_; t++) {
            const size_t row = row0 + t;
            const unsigned short* r = base + (size_t)t * N1_;
            float cw  = b2f(r[4096 + p]);
            float sw  = b2f(swr[(size_t)t * HALF_ + p]);
            float de  = b2f(r[3072 + p]);
            float dob = b2f(r[3328 + p]);
            float ge  = b2f(r[2560 + p]);
            float go  = b2f(r[2816 + p]);
            float ce  = b2f(r[2048 + p]);
            float co  = b2f(r[2304 + p]);
            float a = de * cw, bb = -de * sw, cc = dob * sw, dd = dob * cw;
            float ny0 = a * y0 + bb * y1 + ge * ce;
            float ny1 = cc * y0 + dd * y1 + go * co;
            y0 = ny0; y1 = ny1;
            float qe = b2f(r[3584 + p]);
            float qo = b2f(r[3840 + p]);
            float w1v = mw[row].y;
            G[row * 2048 + 512 + p] = f2b(w1v * silu_(qe * y0));
            G[row * 2048 + 768 + p] = f2b(w1v * silu_(qo * y1));
        }
    }
}

// ================================================================ host
extern "C" void kernel_launch(void* const* d_in, const int* in_sizes, int n_in,
                              void* d_out, int out_size, void* d_ws, size_t ws_size,
                              hipStream_t stream) {
    const float* x       = (const float*)d_in[0];
    const float* W_rf    = (const float*)d_in[1];
    const float* W_ri    = (const float*)d_in[2];
    const float* W_rv    = (const float*)d_in[3];
    const float* W_rq    = (const float*)d_in[4];
    const float* W_ro    = (const float*)d_in[5];
    const float* W_sw    = (const float*)d_in[6];
    const float* W_sg    = (const float*)d_in[7];
    const float* W_som   = (const float*)d_in[8];
    const float* W_sd    = (const float*)d_in[9];
    const float* W_sq    = (const float*)d_in[10];
    const float* W_so    = (const float*)d_in[11];
    const float* W_up    = (const float*)d_in[12];
    const float* W_gate  = (const float*)d_in[13];
    const float* W_down  = (const float*)d_in[14];
    const float* W_mix   = (const float*)d_in[15];
    const float* read_init   = (const float*)d_in[16];
    const float* stable_init = (const float*)d_in[17];

    char* ws = (char*)d_ws;
    size_t off = 0;
    auto alloc = [&](size_t bytes) -> void* {
        void* p = ws + off;
        off = (off + bytes + 255) & ~(size_t)255;
        return p;
    };
    unsigned short* xb   = (unsigned short*)alloc((size_t)BT_ * H_ * 2);
    unsigned short* w1   = (unsigned short*)alloc((size_t)N1_ * K1_ * 2);
    unsigned short* w2   = (unsigned short*)alloc((size_t)N2_ * K2_ * 2);
    unsigned short* proj = (unsigned short*)alloc((size_t)BT_ * N1_ * 2);
    unsigned short* swb  = (unsigned short*)alloc((size_t)BT_ * HALF_ * 2);
    float4*         mw   = (float4*)alloc((size_t)BT_ * 16);
    unsigned short* G    = (unsigned short*)alloc((size_t)BT_ * 2048 * 2);
    float*  rsP     = (float*) alloc((size_t)B_ * NCH_ * S_ * 4);
    float*  rsY     = (float*) alloc((size_t)B_ * NCH_ * S_ * 4);
    float4* ssM     = (float4*)alloc((size_t)B_ * NCH_ * HALF_ * 16);
    float2* ssY     = (float2*)alloc((size_t)B_ * NCH_ * HALF_ * 8);
    float*  rsStart = (float*) alloc((size_t)B_ * NCH_ * S_ * 4);
    float2* ssStart = (float2*)alloc((size_t)B_ * NCH_ * HALF_ * 8);
    if (off > ws_size) return;

    prep_x<<<BT_ / 4, 256, 0, stream>>>(x, W_mix, xb, mw);

    TOps ops;
    int i = 0;
    auto add = [&](const float* s, int Kw, int Nw, int n_ofs, int k_ofs, int which, int ilv) {
        ops.v[i].src = s; ops.v[i].Kw = Kw; ops.v[i].Nw = Nw;
        ops.v[i].n_ofs = n_ofs; ops.v[i].k_ofs = k_ofs; ops.v[i].which = which;
        ops.v[i].ilv = ilv; i++;
    };
    add(W_rf,  1024,  512,    0,    0, 0, 0);
    add(W_ri,  1024,  512,  512,    0, 0, 0);
    add(W_rv,  1024,  512, 1024,    0, 0, 0);
    add(W_rq,  1024,  512, 1536,    0, 0, 0);
    add(W_sw,  1024,  512, 2048,    0, 0, 0);
    add(W_sg,  1024,  512, 2560,    0, 0, 0);
    add(W_sd,  1024,  512, 3072,    0, 0, 0);
    add(W_sq,  1024,  512, 3584,    0, 0, 0);
    add(W_som, 1024,  256, 4096,    0, 0, 0);
    add(W_up,  1024, 1024, 4352,    0, 0, 1);   // interleaved: [up16|gate16] superblocks
    add(W_gate,1024, 1024, 4352,    0, 0, 2);
    add(W_ro,   512, 1024,    0,    0, 1, 0);
    add(W_so,   512, 1024,    0,  512, 1, 0);
    add(W_down,1024, 1024,    0, 1024, 1, 0);
    pack_w_kernel<<<dim3(32, 32, 14), 256, 0, stream>>>(ops, w1, w2);

    gemm_bf16<1><<<dim3(N1_ / 128, BT_ / 128), 256, 0, stream>>>(
        xb, w1, (void*)proj, swb, mw, G, BT_, N1_, K1_);

    scan_pass1<<<dim3(NCH_, B_, 3), 256, 0, stream>>>(proj, swb, rsP, rsY, ssM, ssY);
    scan_pass2<<<12, 256, 0, stream>>>(rsP, rsY, ssM, ssY, read_init, stable_init, rsStart, ssStart);
    scan_pass3<<<dim3(NCH_, B_, 3), 256, 0, stream>>>(proj, swb, rsStart, ssStart, mw, G);

    gemm_bf16<0><<<dim3(N2_ / 128, BT_ / 128), 256, 0, stream>>>(
        G, w2, d_out, nullptr, nullptr, nullptr, BT_, N2_, K2_);
}